// Round 3
// baseline (761.918 us; speedup 1.0000x reference)
//
#include <hip/hip_runtime.h>

#define HW 16384
#define PIf 3.14159265358979323846f
typedef unsigned short ushortt;
typedef unsigned int uint32;
typedef __attribute__((ext_vector_type(8))) short short8;
typedef __attribute__((ext_vector_type(4))) float f32x4;
typedef __attribute__((ext_vector_type(2))) unsigned int uintv2;

// ---------- bf16 raw helpers ----------
__device__ __forceinline__ float bf2f(ushortt b) {
    return __uint_as_float(((unsigned)b) << 16);
}
__device__ __forceinline__ ushortt f2bf(float f) {
    unsigned u = __float_as_uint(f);
    u += 0x7fffu + ((u >> 16) & 1u);   // RNE
    return (ushortt)(u >> 16);
}
__device__ __forceinline__ int brev6(int v) { return (int)(__brev((unsigned)v) >> 26); }

// ---------- butterfly: (A,B) -> (A+B, (A-B)*t) ----------
__device__ __forceinline__ void bfly(float& Ar, float& Ai, float& Br, float& Bi,
                                     float tr, float ti) {
    float sr = Ar + Br, si = Ai + Bi;
    float dr = Ar - Br, di = Ai - Bi;
    Ar = sr; Ai = si;
    Br = dr * tr - di * ti;
    Bi = dr * ti + di * tr;
}

// ---------- cross-lane re-pairing swaps ----------
__device__ __forceinline__ void xswap32(float& a, float& b) {
    uintv2 r = __builtin_amdgcn_permlane32_swap(__float_as_uint(a), __float_as_uint(b), false, false);
    a = __uint_as_float(r.x); b = __uint_as_float(r.y);
}
__device__ __forceinline__ void xswap16(float& a, float& b) {
    uintv2 r = __builtin_amdgcn_permlane16_swap(__float_as_uint(a), __float_as_uint(b), false, false);
    a = __uint_as_float(r.x); b = __uint_as_float(r.y);
}
template<int IMM>
__device__ __forceinline__ void pswap_sw(float& a, float& b, bool up) {
    float sel = up ? a : b;
    float rcv = __int_as_float(__builtin_amdgcn_ds_swizzle(__float_as_int(sel), IMM));
    a = up ? rcv : a;
    b = up ? b : rcv;
}
template<int CTRL>
__device__ __forceinline__ void pswap_dpp(float& a, float& b, bool up) {
    float sel = up ? a : b;
    float rcv = __int_as_float(__builtin_amdgcn_update_dpp(0, __float_as_int(sel), CTRL, 0xF, 0xF, true));
    a = up ? rcv : a;
    b = up ? b : rcv;
}

struct TwSet { float r0,i0,r1,i1,r2,i2,r3,i3,r4,i4,r5,i5; };

__device__ __forceinline__ TwSet load_tw(const float* __restrict__ twr,
                                         const float* __restrict__ twi, int l) {
    TwSet t;
    t.r0 = twr[l];            t.i0 = twi[l];
    t.r1 = twr[(l & 31) << 1]; t.i1 = twi[(l & 31) << 1];
    t.r2 = twr[(l & 15) << 2]; t.i2 = twi[(l & 15) << 2];
    t.r3 = twr[(l & 7)  << 3]; t.i3 = twi[(l & 7)  << 3];
    t.r4 = twr[(l & 3)  << 4]; t.i4 = twi[(l & 3)  << 4];
    t.r5 = twr[(l & 1)  << 5]; t.i5 = twi[(l & 1)  << 5];
    return t;
}

// ---------- pair-swap 128-pt DIF FFT, 2 complex/lane ----------
__device__ __forceinline__ void fft128_ps(float& Ar, float& Ai, float& Br, float& Bi,
                                          const TwSet& t,
                                          bool u8, bool u4, bool u2, bool u1) {
    bfly(Ar, Ai, Br, Bi, t.r0, t.i0);                       // d=64 (in-register)
    xswap32(Ar, Br); xswap32(Ai, Bi);
    bfly(Ar, Ai, Br, Bi, t.r1, t.i1);                       // d=32 (VALU permlane)
    xswap16(Ar, Br); xswap16(Ai, Bi);
    bfly(Ar, Ai, Br, Bi, t.r2, t.i2);                       // d=16 (VALU permlane)
    pswap_sw<0x201F>(Ar, Br, u8); pswap_sw<0x201F>(Ai, Bi, u8);
    bfly(Ar, Ai, Br, Bi, t.r3, t.i3);                       // d=8  (ds_swizzle)
    pswap_sw<0x101F>(Ar, Br, u4); pswap_sw<0x101F>(Ai, Bi, u4);
    bfly(Ar, Ai, Br, Bi, t.r4, t.i4);                       // d=4  (ds_swizzle)
    pswap_dpp<0x4E>(Ar, Br, u2); pswap_dpp<0x4E>(Ai, Bi, u2);
    bfly(Ar, Ai, Br, Bi, t.r5, t.i5);                       // d=2  (DPP)
    pswap_dpp<0xB1>(Ar, Br, u1); pswap_dpp<0xB1>(Ai, Bi, u1);
    {   // d=1, tw = 1
        float sr = Ar + Br, si = Ai + Bi;
        float dr = Ar - Br, di = Ai - Bi;
        Ar = sr; Ai = si; Br = dr; Bi = di;
    }
}

// ---------- Stage A: forward FFT + fftshift + central-mag accumulation ----------
__global__ __launch_bounds__(1024) void fft_fwd(const float* __restrict__ x,
                                                ushortt* __restrict__ xfRe,
                                                ushortt* __restrict__ xfIm,
                                                float* __restrict__ magc) {
    __shared__ float2 sc[128][129];
    __shared__ float twr[64], twi[64];
    int img = blockIdx.x;
    int tid = threadIdx.x, l = tid & 63, wv = tid >> 6;
    if (tid < 64) {
        float s, c;
        sincosf(-PIf * (float)tid / 64.0f, &s, &c);
        twr[tid] = c; twi[tid] = s;
    }
    const float* xi = x + (size_t)img * HW;
    __syncthreads();

    TwSet t = load_tw(twr, twi, l);
    bool u8 = (l & 8) != 0, u4 = (l & 4) != 0, u2 = (l & 2) != 0, u1 = (l & 1) != 0;
    int e = brev6(l);

    // row pass: global -> (pair-swap FFT) -> LDS natural order, 1-row prefetch
    float nar = xi[(wv * 8) * 128 + l];
    float nbr = xi[(wv * 8) * 128 + 64 + l];
    for (int r = 0; r < 8; ++r) {
        int row = wv * 8 + r;
        float Ar = nar, Ai = 0.f, Br = nbr, Bi = 0.f;
        if (r < 7) {
            nar = xi[(row + 1) * 128 + l];
            nbr = xi[(row + 1) * 128 + 64 + l];
        }
        fft128_ps(Ar, Ai, Br, Bi, t, u8, u4, u2, u1);
        sc[row][e]      = make_float2(Ar, Ai);
        sc[row][e + 64] = make_float2(Br, Bi);
    }
    __syncthreads();

    // column pass: LDS -> FFT -> LDS natural 2D-frequency order
    for (int r = 0; r < 8; ++r) {
        int c = wv * 8 + r;
        float2 va = sc[l][c], vb = sc[l + 64][c];
        float Ar = va.x, Ai = va.y, Br = vb.x, Bi = vb.y;
        fft128_ps(Ar, Ai, Br, Bi, t, u8, u4, u2, u1);
        sc[e][c]      = make_float2(Ar, Ai);
        sc[e + 64][c] = make_float2(Br, Bi);
    }
    __syncthreads();

    // coalesced fftshift'd bf16 write (ortho 1/128)
    uint32* oRe = (uint32*)(xfRe + ((size_t)img << 14));
    uint32* oIm = (uint32*)(xfIm + ((size_t)img << 14));
    for (int idx2 = tid; idx2 < 8192; idx2 += 1024) {
        int p = idx2 >> 6, qp = idx2 & 63, q = qp * 2;
        int u  = (p + 64) & 127;
        int v0 = (q + 64) & 127;          // even, pair contiguous
        const float scl = 1.0f / 128.0f;
        float2 e0 = sc[u][v0], e1 = sc[u][v0 + 1];
        uint32 re = (uint32)f2bf(e0.x * scl) | ((uint32)f2bf(e1.x * scl) << 16);
        uint32 im = (uint32)f2bf(e0.y * scl) | ((uint32)f2bf(e1.y * scl) << 16);
        oRe[p * 64 + qp] = re;
        oIm[p * 64 + qp] = im;
    }
    // central 7x7 |xf| accumulation (fp32)
    if (tid < 49) {
        int p = 61 + tid / 7, q = 61 + tid % 7;
        int u = (p + 64) & 127, v = (q + 64) & 127;
        float2 z = sc[u][v];
        float mag = sqrtf(z.x * z.x + z.y * z.y) * (1.0f / 128.0f);
        atomicAdd(&magc[(img >> 8) * 49 + tid], mag);
    }
}

// ---------- Stage B: tiny MLP + anisotropic kernel build ----------
__global__ __launch_bounds__(256) void mlp_kern(const float* __restrict__ magc,
                                                const float* __restrict__ w1,
                                                const float* __restrict__ b1,
                                                const float* __restrict__ w2,
                                                const float* __restrict__ b2,
                                                float* __restrict__ kern) {
    __shared__ float hid[8][32];
    __shared__ float par[8][3];
    __shared__ float kun[8][49];
    __shared__ float ksum[8];
    int tid = threadIdx.x;
    {
        int b = tid >> 5, n = tid & 31;
        float acc = b1[n];
        for (int i = 0; i < 49; ++i)
            acc = fmaf(magc[b * 49 + i] * (1.0f / 256.0f), w1[i * 32 + n], acc);
        hid[b][n] = fmaxf(acc, 0.f);
    }
    __syncthreads();
    if (tid < 24) {
        int b = tid / 3, j = tid % 3;
        float acc = b2[j];
        for (int n = 0; n < 32; ++n) acc = fmaf(hid[b][n], w2[n * 3 + j], acc);
        par[b][j] = acc;
    }
    __syncthreads();
    for (int idx = tid; idx < 392; idx += 256) {
        int b = idx / 49, ij = idx % 49;
        int i = ij / 7, j2 = ij % 7;
        float p0 = par[b][0], p1 = par[b][1], p2 = par[b][2];
        float theta = atan2f(p0, p1) * 0.5f + PIf * 0.5f;
        float lam1 = expf(p2);
        float lam2 = 1.0f / (lam1 + 1e-8f);
        float yy = (float)(i - 3), xx = (float)(j2 - 3);
        float ct, st;
        sincosf(theta, &st, &ct);
        float xr =  xx * ct + yy * st;
        float yr = -xx * st + yy * ct;
        kun[b][ij] = expf(-(xr * xr / (2.f * lam1 * lam1) + yr * yr / (2.f * lam2 * lam2)));
    }
    __syncthreads();
    if (tid < 8) {
        float s = 0.f;
        for (int t = 0; t < 49; ++t) s += kun[tid][t];
        ksum[tid] = s + 1e-8f;
    }
    __syncthreads();
    for (int idx = tid; idx < 392; idx += 256)
        kern[idx] = kun[idx / 49][idx % 49] / ksum[idx / 49];
}

// ---------- Stage C0: transpose xf[c][pix] -> xfT[pix][c] ----------
__global__ __launch_bounds__(256) void xpose(const ushortt* __restrict__ xfRe,
                                             const ushortt* __restrict__ xfIm,
                                             ushortt* __restrict__ xfTRe,
                                             ushortt* __restrict__ xfTIm) {
    __shared__ ushortt T[64 * 65];
    int b = blockIdx.z >> 1, arr = blockIdx.z & 1;
    const ushortt* src = (arr ? xfIm : xfRe) + (size_t)b * (256 * HW);
    ushortt* dst = (arr ? xfTIm : xfTRe) + (size_t)b * (HW * 256);
    int pixBase = blockIdx.x * 64, cBase = blockIdx.y * 64;
    int tid = threadIdx.x;
    #pragma unroll
    for (int i = 0; i < 16; ++i) {
        int idx = tid + i * 256; int c = idx >> 6, p = idx & 63;
        T[c * 65 + p] = src[(size_t)(cBase + c) * HW + pixBase + p];
    }
    __syncthreads();
    #pragma unroll
    for (int i = 0; i < 16; ++i) {
        int idx = tid + i * 256; int p = idx >> 6, c = idx & 63;
        dst[(size_t)(pixBase + p) * 256 + cBase + c] = T[c * 65 + p];
    }
}

// ---------- Stage C: channel mixing via bf16 MFMA ----------
__global__ __launch_bounds__(256) void gemm_mix(const ushortt* __restrict__ xfTRe,
                                                const ushortt* __restrict__ xfTIm,
                                                const float* __restrict__ wr,
                                                ushortt* __restrict__ mixRe,
                                                ushortt* __restrict__ mixIm) {
    __shared__ ushortt lA[2][5120];   // [o=128][k=32] stride 40 ushorts
    __shared__ ushortt lB[2][5120];   // [pix=128][k=32] stride 40
    int tid = threadIdx.x;
    int lane = tid & 63, wave = tid >> 6;
    int wm = wave >> 1, wn = wave & 1;
    int l15 = lane & 15, q4 = lane >> 4;
    int b = blockIdx.z >> 1, part = blockIdx.z & 1;
    const ushortt* X = (part ? xfTIm : xfTRe) + (size_t)b * (HW * 256)
                       + (size_t)blockIdx.x * (128 * 256);
    ushortt* Dst = (part ? mixIm : mixRe) + (size_t)b * (256 * HW)
                   + (size_t)(blockIdx.y * 128) * HW + blockIdx.x * 128;
    const float* W = wr + (blockIdx.y * 128) * 256;

    int srow = tid >> 1, shalf = tid & 1;
    const float*   wRow = W + srow * 256 + shalf * 16;
    const ushortt* xRow = X + srow * 256 + shalf * 16;
    int ldsOff = srow * 40 + shalf * 16;

    float4 wreg[4];
    uint4  xreg[2];
    #pragma unroll
    for (int i = 0; i < 4; ++i) wreg[i] = *(const float4*)(wRow + i * 4);
    #pragma unroll
    for (int i = 0; i < 2; ++i) xreg[i] = *(const uint4*)(xRow + i * 8);

    f32x4 acc[4][4];
    #pragma unroll
    for (int i = 0; i < 4; ++i)
        #pragma unroll
        for (int j = 0; j < 4; ++j)
            #pragma unroll
            for (int k = 0; k < 4; ++k) acc[i][j][k] = 0.f;

    int abase = (wm * 64 + l15) * 40 + q4 * 8;
    int bbase = (wn * 64 + l15) * 40 + q4 * 8;

    for (int kb = 0; kb < 8; ++kb) {
        int bufc = kb & 1;
        float ff[16] = {wreg[0].x, wreg[0].y, wreg[0].z, wreg[0].w,
                        wreg[1].x, wreg[1].y, wreg[1].z, wreg[1].w,
                        wreg[2].x, wreg[2].y, wreg[2].z, wreg[2].w,
                        wreg[3].x, wreg[3].y, wreg[3].z, wreg[3].w};
        uint32 p[8];
        #pragma unroll
        for (int j = 0; j < 8; ++j)
            p[j] = (uint32)f2bf(ff[2 * j]) | ((uint32)f2bf(ff[2 * j + 1]) << 16);
        *(uint4*)&lA[bufc][ldsOff]     = make_uint4(p[0], p[1], p[2], p[3]);
        *(uint4*)&lA[bufc][ldsOff + 8] = make_uint4(p[4], p[5], p[6], p[7]);
        *(uint4*)&lB[bufc][ldsOff]     = xreg[0];
        *(uint4*)&lB[bufc][ldsOff + 8] = xreg[1];
        __syncthreads();
        if (kb < 7) {
            const float*   wN = wRow + (kb + 1) * 32;
            const ushortt* xN = xRow + (kb + 1) * 32;
            #pragma unroll
            for (int i = 0; i < 4; ++i) wreg[i] = *(const float4*)(wN + i * 4);
            #pragma unroll
            for (int i = 0; i < 2; ++i) xreg[i] = *(const uint4*)(xN + i * 8);
        }
        short8 af[4], bf[4];
        #pragma unroll
        for (int f = 0; f < 4; ++f) af[f] = *(const short8*)&lA[bufc][abase + f * 640];
        #pragma unroll
        for (int f = 0; f < 4; ++f) bf[f] = *(const short8*)&lB[bufc][bbase + f * 640];
        #pragma unroll
        for (int fi = 0; fi < 4; ++fi)
            #pragma unroll
            for (int fj = 0; fj < 4; ++fj)
                acc[fi][fj] = __builtin_amdgcn_mfma_f32_16x16x32_bf16(
                    af[fi], bf[fj], acc[fi][fj], 0, 0, 0);
    }
    #pragma unroll
    for (int fi = 0; fi < 4; ++fi) {
        #pragma unroll
        for (int r = 0; r < 4; ++r) {
            int o_l = wm * 64 + fi * 16 + q4 * 4 + r;
            ushortt* dp = Dst + (size_t)o_l * HW + wn * 64 + l15;
            #pragma unroll
            for (int fj = 0; fj < 4; ++fj)
                dp[fj * 16] = f2bf(acc[fi][fj][r]);
        }
    }
}

// ---------- Stage D+E fused: 7x7 conv -> ifftshift -> IFFT (conj) -> +x ----------
// One block per (b,c) plane. Conv reads bf16 mix planes staged in 4 column
// chunks (tiles coexist with the 132KB FFT buffer), writes results directly
// into the FFT buffer pre-shifted & conjugated. Then in-place row/col FFT.
__global__ __launch_bounds__(1024) void conv_ifft(const ushortt* __restrict__ mixRe,
                                                  const ushortt* __restrict__ mixIm,
                                                  const float* __restrict__ kern,
                                                  const float* __restrict__ x,
                                                  float* __restrict__ out) {
    __shared__ float2 sc[128][129];       // 132096 B  (FFT workspace / conv dest)
    __shared__ ushortt tI[2][134][44];    //  23584 B  (bf16 conv tiles, per chunk)
    __shared__ float twr[64], twi[64];    //    512 B

    int img = blockIdx.x;                 // b*256 + c
    int tid = threadIdx.x, l = tid & 63, wv = tid >> 6;
    if (tid < 64) {
        float s, c;
        sincosf(-PIf * (float)tid / 64.0f, &s, &c);
        twr[tid] = c; twi[tid] = s;
    }
    const ushortt* mR = mixRe + ((size_t)img << 14);
    const ushortt* mI = mixIm + ((size_t)img << 14);

    // conv kernel taps (uniform per block -> scalar loads)
    float kv[49];
    const float* kb = kern + (size_t)(img >> 8) * 49;
    #pragma unroll
    for (int i = 0; i < 49; ++i) kv[i] = kb[i];

    // conv thread mapping: y = row, sub -> plane & 8-px strip
    int y   = tid >> 3;
    int sub = tid & 7;
    int pl  = sub >> 2;        // 0 = Re, 1 = Im
    int xq  = sub & 3;         // strip within 32-col chunk
    int x0l = xq * 8;          // tile-local ushort col of strip start

    for (int ch = 0; ch < 4; ++ch) {
        __syncthreads();       // prev chunk's conv reads done (iter0: tw ready)
        // ---- stage chunk tiles: global cols [ch*32-4, ch*32+36) as u32 pairs
        for (int idx = tid; idx < 5360; idx += 1024) {
            int p   = idx / 2680;
            int rem = idx - p * 2680;
            int row = rem / 20;
            int cu  = rem - row * 20;
            int gy  = row - 3;
            int gx0 = ch * 32 - 4 + cu * 2;
            uint32 v = 0u;
            if ((unsigned)gy < 128u && (unsigned)gx0 < 127u) {
                const ushortt* src = p ? mI : mR;
                v = *(const uint32*)(src + gy * 128 + gx0);
            }
            *(uint32*)&tI[p][row][cu * 2] = v;
        }
        __syncthreads();
        // ---- conv 8 px of one row, one plane; write shifted+conj into sc
        float acc[8];
        #pragma unroll
        for (int j = 0; j < 8; ++j) acc[j] = 0.f;
        #pragma unroll
        for (int dy = 0; dy < 7; ++dy) {
            const ushortt* trow = &tI[pl][y + dy][x0l];
            uint2 q0 = *(const uint2*)(trow);
            uint2 q1 = *(const uint2*)(trow + 4);
            uint2 q2 = *(const uint2*)(trow + 8);
            uint2 q3 = *(const uint2*)(trow + 12);
            uint32 w[8] = {q0.x, q0.y, q1.x, q1.y, q2.x, q2.y, q3.x, q3.y};
            float f[16];
            #pragma unroll
            for (int m = 0; m < 8; ++m) {
                f[2 * m]     = __uint_as_float(w[m] << 16);
                f[2 * m + 1] = __uint_as_float(w[m] & 0xffff0000u);
            }
            #pragma unroll
            for (int dx = 0; dx < 7; ++dx) {
                float k = kv[dy * 7 + dx];
                #pragma unroll
                for (int j = 0; j < 8; ++j) acc[j] = fmaf(f[1 + j + dx], k, acc[j]);
            }
        }
        {
            int u  = (y + 64) & 127;
            int vb = ((ch * 32 + x0l) + 64) & 127;   // strip-aligned, no wrap in 8
            if (pl == 0) {
                #pragma unroll
                for (int j = 0; j < 8; ++j) sc[u][vb + j].x = acc[j];
            } else {
                #pragma unroll
                for (int j = 0; j < 8; ++j) sc[u][vb + j].y = -acc[j];
            }
        }
    }
    __syncthreads();           // conv results visible; sc == conj'd/shifted input

    TwSet t = load_tw(twr, twi, l);
    bool u8 = (l & 8) != 0, u4 = (l & 4) != 0, u2 = (l & 2) != 0, u1 = (l & 1) != 0;
    int e = brev6(l);

    // row pass (in place: each row owned by one wave)
    for (int r = 0; r < 8; ++r) {
        int u = wv * 8 + r;
        float2 va = sc[u][l], vbv = sc[u][l + 64];
        float Ar = va.x, Ai = va.y, Br = vbv.x, Bi = vbv.y;
        fft128_ps(Ar, Ai, Br, Bi, t, u8, u4, u2, u1);
        sc[u][e]      = make_float2(Ar, Ai);
        sc[u][e + 64] = make_float2(Br, Bi);
    }
    __syncthreads();

    // column pass (in place: each column owned by one wave)
    for (int r = 0; r < 8; ++r) {
        int c = wv * 8 + r;
        float2 va = sc[l][c], vbv = sc[l + 64][c];
        float Ar = va.x, Ai = va.y, Br = vbv.x, Bi = vbv.y;
        fft128_ps(Ar, Ai, Br, Bi, t, u8, u4, u2, u1);
        sc[e][c]      = make_float2(Ar, Ai);
        sc[e + 64][c] = make_float2(Br, Bi);
    }
    __syncthreads();

    const float* xi = x + (size_t)img * HW;
    float* oo = out + (size_t)img * HW;
    for (int idx2 = tid; idx2 < 8192; idx2 += 1024) {
        int yy = idx2 >> 6, xp = (idx2 & 63) * 2;
        float r0 = sc[yy][xp].x     * (1.0f / 128.0f);
        float r1 = sc[yy][xp + 1].x * (1.0f / 128.0f);
        float2 xv = *(const float2*)(xi + yy * 128 + xp);
        float2 ov; ov.x = r0 + xv.x; ov.y = r1 + xv.y;
        *(float2*)(oo + yy * 128 + xp) = ov;
    }
}

extern "C" void kernel_launch(void* const* d_in, const int* in_sizes, int n_in,
                              void* d_out, int out_size, void* d_ws, size_t ws_size,
                              hipStream_t stream) {
    const float* x  = (const float*)d_in[0];
    const float* w1 = (const float*)d_in[1];
    const float* b1 = (const float*)d_in[2];
    const float* w2 = (const float*)d_in[3];
    const float* b2 = (const float*)d_in[4];
    const float* wr = (const float*)d_in[5];

    char* ws = (char*)d_ws;
    ushortt* xfRe  = (ushortt*)ws;
    ushortt* xfIm  = xfRe + 33554432;
    ushortt* xfTRe = (ushortt*)(ws + 134217728);
    ushortt* xfTIm = xfTRe + 33554432;
    ushortt* mixRe  = xfRe,  *mixIm  = xfIm;    // aliases (xf dead after xpose)
    float* magc = (float*)(ws + 268435456);
    float* kern = (float*)(ws + 268435456 + 2048);

    hipMemsetAsync(magc, 0, 392 * sizeof(float), stream);
    fft_fwd<<<2048, 1024, 0, stream>>>(x, xfRe, xfIm, magc);
    mlp_kern<<<1, 256, 0, stream>>>(magc, w1, b1, w2, b2, kern);
    xpose<<<dim3(256, 4, 16), 256, 0, stream>>>(xfRe, xfIm, xfTRe, xfTIm);
    gemm_mix<<<dim3(128, 2, 16), 256, 0, stream>>>(xfTRe, xfTIm, wr, mixRe, mixIm);
    conv_ifft<<<2048, 1024, 0, stream>>>(mixRe, mixIm, kern, x, (float*)d_out);
}

// Round 4
// 628.251 us; speedup vs baseline: 1.2128x; 1.2128x over previous
//
#include <hip/hip_runtime.h>

#define HW 16384
#define PIf 3.14159265358979323846f
typedef unsigned short ushortt;
typedef unsigned int uint32;
typedef __attribute__((ext_vector_type(8))) short short8;
typedef __attribute__((ext_vector_type(4))) float f32x4;
typedef __attribute__((ext_vector_type(2))) unsigned int uintv2;

// ---------- bf16 raw helpers ----------
__device__ __forceinline__ float bf2f(ushortt b) {
    return __uint_as_float(((unsigned)b) << 16);
}
__device__ __forceinline__ ushortt f2bf(float f) {
    unsigned u = __float_as_uint(f);
    u += 0x7fffu + ((u >> 16) & 1u);   // RNE
    return (ushortt)(u >> 16);
}
__device__ __forceinline__ int brev6(int v) { return (int)(__brev((unsigned)v) >> 26); }

// ---------- butterfly: (A,B) -> (A+B, (A-B)*t) ----------
__device__ __forceinline__ void bfly(float& Ar, float& Ai, float& Br, float& Bi,
                                     float tr, float ti) {
    float sr = Ar + Br, si = Ai + Bi;
    float dr = Ar - Br, di = Ai - Bi;
    Ar = sr; Ai = si;
    Br = dr * tr - di * ti;
    Bi = dr * ti + di * tr;
}

// ---------- cross-lane re-pairing swaps ----------
__device__ __forceinline__ void xswap32(float& a, float& b) {
    uintv2 r = __builtin_amdgcn_permlane32_swap(__float_as_uint(a), __float_as_uint(b), false, false);
    a = __uint_as_float(r.x); b = __uint_as_float(r.y);
}
__device__ __forceinline__ void xswap16(float& a, float& b) {
    uintv2 r = __builtin_amdgcn_permlane16_swap(__float_as_uint(a), __float_as_uint(b), false, false);
    a = __uint_as_float(r.x); b = __uint_as_float(r.y);
}
template<int IMM>
__device__ __forceinline__ void pswap_sw(float& a, float& b, bool up) {
    float sel = up ? a : b;
    float rcv = __int_as_float(__builtin_amdgcn_ds_swizzle(__float_as_int(sel), IMM));
    a = up ? rcv : a;
    b = up ? b : rcv;
}
template<int CTRL>
__device__ __forceinline__ void pswap_dpp(float& a, float& b, bool up) {
    float sel = up ? a : b;
    float rcv = __int_as_float(__builtin_amdgcn_update_dpp(0, __float_as_int(sel), CTRL, 0xF, 0xF, true));
    a = up ? rcv : a;
    b = up ? b : rcv;
}

struct TwSet { float r0,i0,r1,i1,r2,i2,r3,i3,r4,i4,r5,i5; };

__device__ __forceinline__ TwSet load_tw(const float* __restrict__ twr,
                                         const float* __restrict__ twi, int l) {
    TwSet t;
    t.r0 = twr[l];            t.i0 = twi[l];
    t.r1 = twr[(l & 31) << 1]; t.i1 = twi[(l & 31) << 1];
    t.r2 = twr[(l & 15) << 2]; t.i2 = twi[(l & 15) << 2];
    t.r3 = twr[(l & 7)  << 3]; t.i3 = twi[(l & 7)  << 3];
    t.r4 = twr[(l & 3)  << 4]; t.i4 = twi[(l & 3)  << 4];
    t.r5 = twr[(l & 1)  << 5]; t.i5 = twi[(l & 1)  << 5];
    return t;
}

// ---------- pair-swap 128-pt DIF FFT, 2 complex/lane ----------
__device__ __forceinline__ void fft128_ps(float& Ar, float& Ai, float& Br, float& Bi,
                                          const TwSet& t,
                                          bool u8, bool u4, bool u2, bool u1) {
    bfly(Ar, Ai, Br, Bi, t.r0, t.i0);                       // d=64 (in-register)
    xswap32(Ar, Br); xswap32(Ai, Bi);
    bfly(Ar, Ai, Br, Bi, t.r1, t.i1);                       // d=32 (VALU permlane)
    xswap16(Ar, Br); xswap16(Ai, Bi);
    bfly(Ar, Ai, Br, Bi, t.r2, t.i2);                       // d=16 (VALU permlane)
    pswap_sw<0x201F>(Ar, Br, u8); pswap_sw<0x201F>(Ai, Bi, u8);
    bfly(Ar, Ai, Br, Bi, t.r3, t.i3);                       // d=8  (ds_swizzle)
    pswap_sw<0x101F>(Ar, Br, u4); pswap_sw<0x101F>(Ai, Bi, u4);
    bfly(Ar, Ai, Br, Bi, t.r4, t.i4);                       // d=4  (ds_swizzle)
    pswap_dpp<0x4E>(Ar, Br, u2); pswap_dpp<0x4E>(Ai, Bi, u2);
    bfly(Ar, Ai, Br, Bi, t.r5, t.i5);                       // d=2  (DPP)
    pswap_dpp<0xB1>(Ar, Br, u1); pswap_dpp<0xB1>(Ai, Bi, u1);
    {   // d=1, tw = 1
        float sr = Ar + Br, si = Ai + Bi;
        float dr = Ar - Br, di = Ai - Bi;
        Ar = sr; Ai = si; Br = dr; Bi = di;
    }
}

// ---------- Stage A: forward FFT + fftshift + central-mag accumulation ----------
__global__ __launch_bounds__(1024) void fft_fwd(const float* __restrict__ x,
                                                ushortt* __restrict__ xfRe,
                                                ushortt* __restrict__ xfIm,
                                                float* __restrict__ magc) {
    __shared__ float2 sc[128][129];
    __shared__ float twr[64], twi[64];
    int img = blockIdx.x;
    int tid = threadIdx.x, l = tid & 63, wv = tid >> 6;
    if (tid < 64) {
        float s, c;
        sincosf(-PIf * (float)tid / 64.0f, &s, &c);
        twr[tid] = c; twi[tid] = s;
    }
    const float* xi = x + (size_t)img * HW;
    __syncthreads();

    TwSet t = load_tw(twr, twi, l);
    bool u8 = (l & 8) != 0, u4 = (l & 4) != 0, u2 = (l & 2) != 0, u1 = (l & 1) != 0;
    int e = brev6(l);

    // row pass: global -> (pair-swap FFT) -> LDS natural order, 1-row prefetch
    float nar = xi[(wv * 8) * 128 + l];
    float nbr = xi[(wv * 8) * 128 + 64 + l];
    for (int r = 0; r < 8; ++r) {
        int row = wv * 8 + r;
        float Ar = nar, Ai = 0.f, Br = nbr, Bi = 0.f;
        if (r < 7) {
            nar = xi[(row + 1) * 128 + l];
            nbr = xi[(row + 1) * 128 + 64 + l];
        }
        fft128_ps(Ar, Ai, Br, Bi, t, u8, u4, u2, u1);
        sc[row][e]      = make_float2(Ar, Ai);
        sc[row][e + 64] = make_float2(Br, Bi);
    }
    __syncthreads();

    // column pass: LDS -> FFT -> LDS natural 2D-frequency order
    for (int r = 0; r < 8; ++r) {
        int c = wv * 8 + r;
        float2 va = sc[l][c], vb = sc[l + 64][c];
        float Ar = va.x, Ai = va.y, Br = vb.x, Bi = vb.y;
        fft128_ps(Ar, Ai, Br, Bi, t, u8, u4, u2, u1);
        sc[e][c]      = make_float2(Ar, Ai);
        sc[e + 64][c] = make_float2(Br, Bi);
    }
    __syncthreads();

    // coalesced fftshift'd bf16 write (ortho 1/128)
    uint32* oRe = (uint32*)(xfRe + ((size_t)img << 14));
    uint32* oIm = (uint32*)(xfIm + ((size_t)img << 14));
    for (int idx2 = tid; idx2 < 8192; idx2 += 1024) {
        int p = idx2 >> 6, qp = idx2 & 63, q = qp * 2;
        int u  = (p + 64) & 127;
        int v0 = (q + 64) & 127;          // even, pair contiguous
        const float scl = 1.0f / 128.0f;
        float2 e0 = sc[u][v0], e1 = sc[u][v0 + 1];
        uint32 re = (uint32)f2bf(e0.x * scl) | ((uint32)f2bf(e1.x * scl) << 16);
        uint32 im = (uint32)f2bf(e0.y * scl) | ((uint32)f2bf(e1.y * scl) << 16);
        oRe[p * 64 + qp] = re;
        oIm[p * 64 + qp] = im;
    }
    // central 7x7 |xf| accumulation (fp32)
    if (tid < 49) {
        int p = 61 + tid / 7, q = 61 + tid % 7;
        int u = (p + 64) & 127, v = (q + 64) & 127;
        float2 z = sc[u][v];
        float mag = sqrtf(z.x * z.x + z.y * z.y) * (1.0f / 128.0f);
        atomicAdd(&magc[(img >> 8) * 49 + tid], mag);
    }
}

// ---------- Stage B: tiny MLP + anisotropic kernel build ----------
__global__ __launch_bounds__(256) void mlp_kern(const float* __restrict__ magc,
                                                const float* __restrict__ w1,
                                                const float* __restrict__ b1,
                                                const float* __restrict__ w2,
                                                const float* __restrict__ b2,
                                                float* __restrict__ kern) {
    __shared__ float hid[8][32];
    __shared__ float par[8][3];
    __shared__ float kun[8][49];
    __shared__ float ksum[8];
    int tid = threadIdx.x;
    {
        int b = tid >> 5, n = tid & 31;
        float acc = b1[n];
        for (int i = 0; i < 49; ++i)
            acc = fmaf(magc[b * 49 + i] * (1.0f / 256.0f), w1[i * 32 + n], acc);
        hid[b][n] = fmaxf(acc, 0.f);
    }
    __syncthreads();
    if (tid < 24) {
        int b = tid / 3, j = tid % 3;
        float acc = b2[j];
        for (int n = 0; n < 32; ++n) acc = fmaf(hid[b][n], w2[n * 3 + j], acc);
        par[b][j] = acc;
    }
    __syncthreads();
    for (int idx = tid; idx < 392; idx += 256) {
        int b = idx / 49, ij = idx % 49;
        int i = ij / 7, j2 = ij % 7;
        float p0 = par[b][0], p1 = par[b][1], p2 = par[b][2];
        float theta = atan2f(p0, p1) * 0.5f + PIf * 0.5f;
        float lam1 = expf(p2);
        float lam2 = 1.0f / (lam1 + 1e-8f);
        float yy = (float)(i - 3), xx = (float)(j2 - 3);
        float ct, st;
        sincosf(theta, &st, &ct);
        float xr =  xx * ct + yy * st;
        float yr = -xx * st + yy * ct;
        kun[b][ij] = expf(-(xr * xr / (2.f * lam1 * lam1) + yr * yr / (2.f * lam2 * lam2)));
    }
    __syncthreads();
    if (tid < 8) {
        float s = 0.f;
        for (int t = 0; t < 49; ++t) s += kun[tid][t];
        ksum[tid] = s + 1e-8f;
    }
    __syncthreads();
    for (int idx = tid; idx < 392; idx += 256)
        kern[idx] = kun[idx / 49][idx % 49] / ksum[idx / 49];
}

// ---------- Stage C: channel mixing via bf16 MFMA, direct [c][pix] input ----------
// B (=X) is transposed during LDS staging: each thread loads 2 k-rows x 8 pix
// (coalesced uint4), packs k-pairs into dwords, scatters 8 ds_write_b32 into a
// [pix][k] tile whose k-octet index is XOR-swizzled by (pix>>3)&3 -> 4-way
// write conflicts instead of 16-way, and fragment reads stay contiguous b128.
__global__ __launch_bounds__(256) void gemm_mix(const ushortt* __restrict__ xfRe,
                                                const ushortt* __restrict__ xfIm,
                                                const float* __restrict__ wr,
                                                ushortt* __restrict__ mixRe,
                                                ushortt* __restrict__ mixIm) {
    __shared__ ushortt lA[2][5120];   // [o=128][k=32] stride 40 ushorts
    __shared__ uint32  lB[2][2560];   // [pix=128][k2=16(+4 pad)] dwords, swizzled
    int tid = threadIdx.x;
    int lane = tid & 63, wave = tid >> 6;
    int wm = wave >> 1, wn = wave & 1;
    int l15 = lane & 15, q4 = lane >> 4;
    int b = blockIdx.z >> 1, part = blockIdx.z & 1;
    const ushortt* Xb = (part ? xfIm : xfRe) + (size_t)b * (256 * HW)
                        + blockIdx.x * 128;
    ushortt* Dst = (part ? mixIm : mixRe) + (size_t)b * (256 * HW)
                   + (size_t)(blockIdx.y * 128) * HW + blockIdx.x * 128;
    const float* W = wr + (blockIdx.y * 128) * 256;

    // A staging mapping (unchanged)
    int srow = tid >> 1, shalf = tid & 1;
    const float* wRow = W + srow * 256 + shalf * 16;
    int ldsOffA = srow * 40 + shalf * 16;

    // B staging mapping: kt = k-pair index (k = 2*kt, 2*kt+1), pq = pixel-octet
    int kt = tid >> 4;                 // 0..15
    int pq = tid & 15;                 // 0..15
    int kswz = kt ^ ((pq & 3) << 2);   // octet-bit XOR swizzle
    int rowbase = pq * 160;            // pq*8 rows * 20 dwords

    float4 wreg[4];
    uint4  a0, a1;
    #pragma unroll
    for (int i = 0; i < 4; ++i) wreg[i] = *(const float4*)(wRow + i * 4);
    {
        const ushortt* xp = Xb + (size_t)(2 * kt) * HW + pq * 8;
        a0 = *(const uint4*)xp;
        a1 = *(const uint4*)(xp + HW);
    }

    f32x4 acc[4][4];
    #pragma unroll
    for (int i = 0; i < 4; ++i)
        #pragma unroll
        for (int j = 0; j < 4; ++j)
            #pragma unroll
            for (int k = 0; k < 4; ++k) acc[i][j][k] = 0.f;

    int abase = (wm * 64 + l15) * 40 + q4 * 8;
    int baddr[4];
    #pragma unroll
    for (int f = 0; f < 4; ++f) {
        int pf = wn * 64 + f * 16 + l15;
        baddr[f] = pf * 40 + ((q4 ^ ((pf >> 3) & 3)) << 3);
    }

    for (int kb = 0; kb < 8; ++kb) {
        int bufc = kb & 1;
        // ---- A: fp32 -> bf16 pack, vectorized store
        {
            float ff[16] = {wreg[0].x, wreg[0].y, wreg[0].z, wreg[0].w,
                            wreg[1].x, wreg[1].y, wreg[1].z, wreg[1].w,
                            wreg[2].x, wreg[2].y, wreg[2].z, wreg[2].w,
                            wreg[3].x, wreg[3].y, wreg[3].z, wreg[3].w};
            uint32 p[8];
            #pragma unroll
            for (int j = 0; j < 8; ++j)
                p[j] = (uint32)f2bf(ff[2 * j]) | ((uint32)f2bf(ff[2 * j + 1]) << 16);
            *(uint4*)&lA[bufc][ldsOffA]     = make_uint4(p[0], p[1], p[2], p[3]);
            *(uint4*)&lA[bufc][ldsOffA + 8] = make_uint4(p[4], p[5], p[6], p[7]);
        }
        // ---- B: interleave k-pairs, swizzled dword scatter (LDS transpose)
        {
            uint32 d[8];
            d[0] = (a0.x & 0xffffu) | (a1.x << 16);
            d[1] = (a0.x >> 16)     | (a1.x & 0xffff0000u);
            d[2] = (a0.y & 0xffffu) | (a1.y << 16);
            d[3] = (a0.y >> 16)     | (a1.y & 0xffff0000u);
            d[4] = (a0.z & 0xffffu) | (a1.z << 16);
            d[5] = (a0.z >> 16)     | (a1.z & 0xffff0000u);
            d[6] = (a0.w & 0xffffu) | (a1.w << 16);
            d[7] = (a0.w >> 16)     | (a1.w & 0xffff0000u);
            uint32* lb = lB[bufc];
            #pragma unroll
            for (int j = 0; j < 8; ++j) lb[rowbase + j * 20 + kswz] = d[j];
        }
        __syncthreads();
        if (kb < 7) {
            const float* wN = wRow + (kb + 1) * 32;
            #pragma unroll
            for (int i = 0; i < 4; ++i) wreg[i] = *(const float4*)(wN + i * 4);
            const ushortt* xp = Xb + (size_t)((kb + 1) * 32 + 2 * kt) * HW + pq * 8;
            a0 = *(const uint4*)xp;
            a1 = *(const uint4*)(xp + HW);
        }
        short8 af[4], bf[4];
        const ushortt* lbU = (const ushortt*)lB[bufc];
        #pragma unroll
        for (int f = 0; f < 4; ++f) af[f] = *(const short8*)&lA[bufc][abase + f * 640];
        #pragma unroll
        for (int f = 0; f < 4; ++f) bf[f] = *(const short8*)&lbU[baddr[f]];
        #pragma unroll
        for (int fi = 0; fi < 4; ++fi)
            #pragma unroll
            for (int fj = 0; fj < 4; ++fj)
                acc[fi][fj] = __builtin_amdgcn_mfma_f32_16x16x32_bf16(
                    af[fi], bf[fj], acc[fi][fj], 0, 0, 0);
    }
    #pragma unroll
    for (int fi = 0; fi < 4; ++fi) {
        #pragma unroll
        for (int r = 0; r < 4; ++r) {
            int o_l = wm * 64 + fi * 16 + q4 * 4 + r;
            ushortt* dp = Dst + (size_t)o_l * HW + wn * 64 + l15;
            #pragma unroll
            for (int fj = 0; fj < 4; ++fj)
                dp[fj * 16] = f2bf(acc[fi][fj][r]);
        }
    }
}

// ---------- Stage D: 7x7 zero-padded conv, register-blocked 2x8/thread ----------
__global__ __launch_bounds__(256) void conv7(const ushortt* __restrict__ mixRe,
                                             const ushortt* __restrict__ mixIm,
                                             const float* __restrict__ kern,
                                             ushortt* __restrict__ outRe,
                                             ushortt* __restrict__ outIm) {
    __shared__ float tile[70 * 73];
    int b = blockIdx.z;
    int plane = blockIdx.y;
    int part = plane >> 8;
    size_t pbase = ((size_t)(b * 256 + (plane & 255))) << 14;
    const ushortt* src = (part ? mixIm : mixRe) + pbase;
    ushortt* dst = (part ? outIm : outRe) + pbase;
    int ty = (blockIdx.x >> 1) * 64, tx = (blockIdx.x & 1) * 64;
    int tid = threadIdx.x;
    float kv[49];
    #pragma unroll
    for (int i = 0; i < 49; ++i) kv[i] = kern[b * 49 + i];
    for (int idx = tid; idx < 4900; idx += 256) {
        int i = idx / 70, j = idx - i * 70;
        int r = ty + i - 3, c = tx + j - 3;
        float v = 0.f;
        if ((unsigned)r < 128u && (unsigned)c < 128u) v = bf2f(src[r * 128 + c]);
        tile[i * 73 + j] = v;
    }
    __syncthreads();
    int ox = (tid & 7) * 8, oy = (tid >> 3) * 2;
    float a0[8], a1[8];
    #pragma unroll
    for (int j = 0; j < 8; ++j) { a0[j] = 0.f; a1[j] = 0.f; }
    #pragma unroll
    for (int dyy = 0; dyy < 8; ++dyy) {
        float row[14];
        #pragma unroll
        for (int j = 0; j < 14; ++j) row[j] = tile[(oy + dyy) * 73 + ox + j];
        if (dyy < 7) {
            #pragma unroll
            for (int dx = 0; dx < 7; ++dx) {
                float k = kv[dyy * 7 + dx];
                #pragma unroll
                for (int j = 0; j < 8; ++j) a0[j] = fmaf(row[dx + j], k, a0[j]);
            }
        }
        if (dyy >= 1) {
            #pragma unroll
            for (int dx = 0; dx < 7; ++dx) {
                float k = kv[(dyy - 1) * 7 + dx];
                #pragma unroll
                for (int j = 0; j < 8; ++j) a1[j] = fmaf(row[dx + j], k, a1[j]);
            }
        }
    }
    uint32 s0[4], s1[4];
    #pragma unroll
    for (int j = 0; j < 4; ++j) {
        s0[j] = (uint32)f2bf(a0[2 * j]) | ((uint32)f2bf(a0[2 * j + 1]) << 16);
        s1[j] = (uint32)f2bf(a1[2 * j]) | ((uint32)f2bf(a1[2 * j + 1]) << 16);
    }
    *(uint4*)(dst + (ty + oy) * 128 + tx + ox)     = make_uint4(s0[0], s0[1], s0[2], s0[3]);
    *(uint4*)(dst + (ty + oy + 1) * 128 + tx + ox) = make_uint4(s1[0], s1[1], s1[2], s1[3]);
}

// ---------- Stage E: ifftshift + inverse FFT (conj trick) + residual add ----------
__global__ __launch_bounds__(1024) void ifft_add(const ushortt* __restrict__ convRe,
                                                 const ushortt* __restrict__ convIm,
                                                 const float* __restrict__ x,
                                                 float* __restrict__ out) {
    __shared__ float2 sc[128][129];
    __shared__ float twr[64], twi[64];
    int img = blockIdx.x;
    int tid = threadIdx.x, l = tid & 63, wv = tid >> 6;
    if (tid < 64) {
        float s, c;
        sincosf(-PIf * (float)tid / 64.0f, &s, &c);
        twr[tid] = c; twi[tid] = s;
    }
    const ushortt* cr = convRe + ((size_t)img << 14);
    const ushortt* ci = convIm + ((size_t)img << 14);
    __syncthreads();

    TwSet t = load_tw(twr, twi, l);
    bool u8 = (l & 8) != 0, u4 = (l & 4) != 0, u2 = (l & 2) != 0, u1 = (l & 1) != 0;
    int e = brev6(l);

    // row pass: ifftshift gather from global (conj), pair-swap FFT, LDS natural
    {
        int p0 = ((wv * 8) + 64) & 127;
        float nar = bf2f(cr[p0 * 128 + 64 + l]), nai = bf2f(ci[p0 * 128 + 64 + l]);
        float nbr = bf2f(cr[p0 * 128 + l]),      nbi = bf2f(ci[p0 * 128 + l]);
        for (int r = 0; r < 8; ++r) {
            int u = wv * 8 + r;
            float Ar = nar, Ai = -nai, Br = nbr, Bi = -nbi;
            if (r < 7) {
                int p = ((u + 1) + 64) & 127;
                nar = bf2f(cr[p * 128 + 64 + l]); nai = bf2f(ci[p * 128 + 64 + l]);
                nbr = bf2f(cr[p * 128 + l]);      nbi = bf2f(ci[p * 128 + l]);
            }
            fft128_ps(Ar, Ai, Br, Bi, t, u8, u4, u2, u1);
            sc[u][e]      = make_float2(Ar, Ai);
            sc[u][e + 64] = make_float2(Br, Bi);
        }
    }
    __syncthreads();

    // column pass
    for (int r = 0; r < 8; ++r) {
        int c = wv * 8 + r;
        float2 va = sc[l][c], vbv = sc[l + 64][c];
        float Ar = va.x, Ai = va.y, Br = vbv.x, Bi = vbv.y;
        fft128_ps(Ar, Ai, Br, Bi, t, u8, u4, u2, u1);
        sc[e][c]      = make_float2(Ar, Ai);
        sc[e + 64][c] = make_float2(Br, Bi);
    }
    __syncthreads();

    const float* xi = x + (size_t)img * HW;
    float* oo = out + (size_t)img * HW;
    for (int idx2 = tid; idx2 < 8192; idx2 += 1024) {
        int y = idx2 >> 6, xp = (idx2 & 63) * 2;
        float r0 = sc[y][xp].x     * (1.0f / 128.0f);
        float r1 = sc[y][xp + 1].x * (1.0f / 128.0f);
        float2 xv = *(const float2*)(xi + y * 128 + xp);
        float2 ov; ov.x = r0 + xv.x; ov.y = r1 + xv.y;
        *(float2*)(oo + y * 128 + xp) = ov;
    }
}

extern "C" void kernel_launch(void* const* d_in, const int* in_sizes, int n_in,
                              void* d_out, int out_size, void* d_ws, size_t ws_size,
                              hipStream_t stream) {
    const float* x  = (const float*)d_in[0];
    const float* w1 = (const float*)d_in[1];
    const float* b1 = (const float*)d_in[2];
    const float* w2 = (const float*)d_in[3];
    const float* b2 = (const float*)d_in[4];
    const float* wr = (const float*)d_in[5];

    char* ws = (char*)d_ws;
    ushortt* xfRe  = (ushortt*)ws;                       // 64 MiB
    ushortt* xfIm  = xfRe + 33554432;                    // 64 MiB
    ushortt* mixRe = (ushortt*)(ws + 134217728);         // 64 MiB (separate: gemm in != out)
    ushortt* mixIm = mixRe + 33554432;                   // 64 MiB
    ushortt* convRe = xfRe, *convIm = xfIm;              // aliases (xf dead after gemm)
    float* magc = (float*)(ws + 268435456);
    float* kern = (float*)(ws + 268435456 + 2048);

    hipMemsetAsync(magc, 0, 392 * sizeof(float), stream);
    fft_fwd<<<2048, 1024, 0, stream>>>(x, xfRe, xfIm, magc);
    mlp_kern<<<1, 256, 0, stream>>>(magc, w1, b1, w2, b2, kern);
    gemm_mix<<<dim3(128, 2, 16), 256, 0, stream>>>(xfRe, xfIm, wr, mixRe, mixIm);
    conv7<<<dim3(4, 512, 8), 256, 0, stream>>>(mixRe, mixIm, kern, convRe, convIm);
    ifft_add<<<2048, 1024, 0, stream>>>(convRe, convIm, x, (float*)d_out);
}

// Round 5
// 595.772 us; speedup vs baseline: 1.2789x; 1.0545x over previous
//
#include <hip/hip_runtime.h>

#define HW 16384
#define PIf 3.14159265358979323846f
typedef unsigned short ushortt;
typedef unsigned int uint32;
typedef __attribute__((ext_vector_type(8))) short short8;
typedef __attribute__((ext_vector_type(4))) float f32x4;
typedef __attribute__((ext_vector_type(2))) float f32x2;
typedef __attribute__((ext_vector_type(2))) unsigned int uintv2;

// ---------- bf16 raw helpers ----------
__device__ __forceinline__ float bf2f(ushortt b) {
    return __uint_as_float(((unsigned)b) << 16);
}
__device__ __forceinline__ ushortt f2bf(float f) {
    unsigned u = __float_as_uint(f);
    u += 0x7fffu + ((u >> 16) & 1u);   // RNE
    return (ushortt)(u >> 16);
}
__device__ __forceinline__ int brev6(int v) { return (int)(__brev((unsigned)v) >> 26); }

// ---------- butterfly: (A,B) -> (A+B, (A-B)*t) ----------
__device__ __forceinline__ void bfly(float& Ar, float& Ai, float& Br, float& Bi,
                                     float tr, float ti) {
    float sr = Ar + Br, si = Ai + Bi;
    float dr = Ar - Br, di = Ai - Bi;
    Ar = sr; Ai = si;
    Br = dr * tr - di * ti;
    Bi = dr * ti + di * tr;
}

// ---------- cross-lane re-pairing swaps ----------
__device__ __forceinline__ void xswap32(float& a, float& b) {
    uintv2 r = __builtin_amdgcn_permlane32_swap(__float_as_uint(a), __float_as_uint(b), false, false);
    a = __uint_as_float(r.x); b = __uint_as_float(r.y);
}
__device__ __forceinline__ void xswap16(float& a, float& b) {
    uintv2 r = __builtin_amdgcn_permlane16_swap(__float_as_uint(a), __float_as_uint(b), false, false);
    a = __uint_as_float(r.x); b = __uint_as_float(r.y);
}
template<int IMM>
__device__ __forceinline__ void pswap_sw(float& a, float& b, bool up) {
    float sel = up ? a : b;
    float rcv = __int_as_float(__builtin_amdgcn_ds_swizzle(__float_as_int(sel), IMM));
    a = up ? rcv : a;
    b = up ? b : rcv;
}
template<int CTRL>
__device__ __forceinline__ void pswap_dpp(float& a, float& b, bool up) {
    float sel = up ? a : b;
    float rcv = __int_as_float(__builtin_amdgcn_update_dpp(0, __float_as_int(sel), CTRL, 0xF, 0xF, true));
    a = up ? rcv : a;
    b = up ? b : rcv;
}

struct TwSet { float r0,i0,r1,i1,r2,i2,r3,i3,r4,i4,r5,i5; };

__device__ __forceinline__ TwSet load_tw(const float* __restrict__ twr,
                                         const float* __restrict__ twi, int l) {
    TwSet t;
    t.r0 = twr[l];            t.i0 = twi[l];
    t.r1 = twr[(l & 31) << 1]; t.i1 = twi[(l & 31) << 1];
    t.r2 = twr[(l & 15) << 2]; t.i2 = twi[(l & 15) << 2];
    t.r3 = twr[(l & 7)  << 3]; t.i3 = twi[(l & 7)  << 3];
    t.r4 = twr[(l & 3)  << 4]; t.i4 = twi[(l & 3)  << 4];
    t.r5 = twr[(l & 1)  << 5]; t.i5 = twi[(l & 1)  << 5];
    return t;
}

// ---------- pair-swap 128-pt DIF FFT, 2 complex/lane ----------
__device__ __forceinline__ void fft128_ps(float& Ar, float& Ai, float& Br, float& Bi,
                                          const TwSet& t,
                                          bool u8, bool u4, bool u2, bool u1) {
    bfly(Ar, Ai, Br, Bi, t.r0, t.i0);                       // d=64 (in-register)
    xswap32(Ar, Br); xswap32(Ai, Bi);
    bfly(Ar, Ai, Br, Bi, t.r1, t.i1);                       // d=32 (VALU permlane)
    xswap16(Ar, Br); xswap16(Ai, Bi);
    bfly(Ar, Ai, Br, Bi, t.r2, t.i2);                       // d=16 (VALU permlane)
    pswap_sw<0x201F>(Ar, Br, u8); pswap_sw<0x201F>(Ai, Bi, u8);
    bfly(Ar, Ai, Br, Bi, t.r3, t.i3);                       // d=8  (ds_swizzle)
    pswap_sw<0x101F>(Ar, Br, u4); pswap_sw<0x101F>(Ai, Bi, u4);
    bfly(Ar, Ai, Br, Bi, t.r4, t.i4);                       // d=4  (ds_swizzle)
    pswap_dpp<0x4E>(Ar, Br, u2); pswap_dpp<0x4E>(Ai, Bi, u2);
    bfly(Ar, Ai, Br, Bi, t.r5, t.i5);                       // d=2  (DPP)
    pswap_dpp<0xB1>(Ar, Br, u1); pswap_dpp<0xB1>(Ai, Bi, u1);
    {   // d=1, tw = 1
        float sr = Ar + Br, si = Ai + Bi;
        float dr = Ar - Br, di = Ai - Bi;
        Ar = sr; Ai = si; Br = dr; Bi = di;
    }
}

// ---------- Stage A: forward FFT + fftshift + central-mag accumulation ----------
__global__ __launch_bounds__(1024) void fft_fwd(const float* __restrict__ x,
                                                ushortt* __restrict__ xfRe,
                                                ushortt* __restrict__ xfIm,
                                                float* __restrict__ magc) {
    __shared__ float2 sc[128][129];
    __shared__ float twr[64], twi[64];
    int img = blockIdx.x;
    int tid = threadIdx.x, l = tid & 63, wv = tid >> 6;
    if (tid < 64) {
        float s, c;
        sincosf(-PIf * (float)tid / 64.0f, &s, &c);
        twr[tid] = c; twi[tid] = s;
    }
    const float* xi = x + (size_t)img * HW;
    __syncthreads();

    TwSet t = load_tw(twr, twi, l);
    bool u8 = (l & 8) != 0, u4 = (l & 4) != 0, u2 = (l & 2) != 0, u1 = (l & 1) != 0;
    int e = brev6(l);

    // row pass: global -> (pair-swap FFT) -> LDS natural order, 1-row prefetch
    float nar = xi[(wv * 8) * 128 + l];
    float nbr = xi[(wv * 8) * 128 + 64 + l];
    for (int r = 0; r < 8; ++r) {
        int row = wv * 8 + r;
        float Ar = nar, Ai = 0.f, Br = nbr, Bi = 0.f;
        if (r < 7) {
            nar = xi[(row + 1) * 128 + l];
            nbr = xi[(row + 1) * 128 + 64 + l];
        }
        fft128_ps(Ar, Ai, Br, Bi, t, u8, u4, u2, u1);
        sc[row][e]      = make_float2(Ar, Ai);
        sc[row][e + 64] = make_float2(Br, Bi);
    }
    __syncthreads();

    // column pass: LDS -> FFT -> LDS natural 2D-frequency order
    for (int r = 0; r < 8; ++r) {
        int c = wv * 8 + r;
        float2 va = sc[l][c], vb = sc[l + 64][c];
        float Ar = va.x, Ai = va.y, Br = vb.x, Bi = vb.y;
        fft128_ps(Ar, Ai, Br, Bi, t, u8, u4, u2, u1);
        sc[e][c]      = make_float2(Ar, Ai);
        sc[e + 64][c] = make_float2(Br, Bi);
    }
    __syncthreads();

    // coalesced fftshift'd bf16 write (ortho 1/128)
    uint32* oRe = (uint32*)(xfRe + ((size_t)img << 14));
    uint32* oIm = (uint32*)(xfIm + ((size_t)img << 14));
    for (int idx2 = tid; idx2 < 8192; idx2 += 1024) {
        int p = idx2 >> 6, qp = idx2 & 63, q = qp * 2;
        int u  = (p + 64) & 127;
        int v0 = (q + 64) & 127;          // even, pair contiguous
        const float scl = 1.0f / 128.0f;
        float2 e0 = sc[u][v0], e1 = sc[u][v0 + 1];
        uint32 re = (uint32)f2bf(e0.x * scl) | ((uint32)f2bf(e1.x * scl) << 16);
        uint32 im = (uint32)f2bf(e0.y * scl) | ((uint32)f2bf(e1.y * scl) << 16);
        oRe[p * 64 + qp] = re;
        oIm[p * 64 + qp] = im;
    }
    // central 7x7 |xf| accumulation (fp32)
    if (tid < 49) {
        int p = 61 + tid / 7, q = 61 + tid % 7;
        int u = (p + 64) & 127, v = (q + 64) & 127;
        float2 z = sc[u][v];
        float mag = sqrtf(z.x * z.x + z.y * z.y) * (1.0f / 128.0f);
        atomicAdd(&magc[(img >> 8) * 49 + tid], mag);
    }
}

// ---------- Stage B: tiny MLP + anisotropic kernel build ----------
// Emits PRE-PAIRED conv taps: kern_pk[b][dyy in 0..7][dx] =
//   ( dyy<7 ? k[dyy][dx] : 0 ,  dyy>=1 ? k[dyy-1][dx] : 0 )
// so conv7 can do one v_pk_fma_f32 per (input row, dx) covering both output rows.
__global__ __launch_bounds__(256) void mlp_kern(const float* __restrict__ magc,
                                                const float* __restrict__ w1,
                                                const float* __restrict__ b1,
                                                const float* __restrict__ w2,
                                                const float* __restrict__ b2,
                                                float2* __restrict__ kern_pk) {
    __shared__ float hid[8][32];
    __shared__ float par[8][3];
    __shared__ float kun[8][49];
    __shared__ float ksum[8];
    int tid = threadIdx.x;
    {
        int b = tid >> 5, n = tid & 31;
        float acc = b1[n];
        for (int i = 0; i < 49; ++i)
            acc = fmaf(magc[b * 49 + i] * (1.0f / 256.0f), w1[i * 32 + n], acc);
        hid[b][n] = fmaxf(acc, 0.f);
    }
    __syncthreads();
    if (tid < 24) {
        int b = tid / 3, j = tid % 3;
        float acc = b2[j];
        for (int n = 0; n < 32; ++n) acc = fmaf(hid[b][n], w2[n * 3 + j], acc);
        par[b][j] = acc;
    }
    __syncthreads();
    for (int idx = tid; idx < 392; idx += 256) {
        int b = idx / 49, ij = idx % 49;
        int i = ij / 7, j2 = ij % 7;
        float p0 = par[b][0], p1 = par[b][1], p2 = par[b][2];
        float theta = atan2f(p0, p1) * 0.5f + PIf * 0.5f;
        float lam1 = expf(p2);
        float lam2 = 1.0f / (lam1 + 1e-8f);
        float yy = (float)(i - 3), xx = (float)(j2 - 3);
        float ct, st;
        sincosf(theta, &st, &ct);
        float xr =  xx * ct + yy * st;
        float yr = -xx * st + yy * ct;
        kun[b][ij] = expf(-(xr * xr / (2.f * lam1 * lam1) + yr * yr / (2.f * lam2 * lam2)));
    }
    __syncthreads();
    if (tid < 8) {
        float s = 0.f;
        for (int t = 0; t < 49; ++t) s += kun[tid][t];
        ksum[tid] = s + 1e-8f;
    }
    __syncthreads();
    for (int idx = tid; idx < 448; idx += 256) {
        int b  = idx / 56;
        int r7 = idx - b * 56;
        int rr = r7 / 7, dx = r7 - rr * 7;
        float inv = 1.0f / ksum[b];
        float v0 = (rr < 7)  ? kun[b][rr * 7 + dx] * inv       : 0.f;
        float v1 = (rr >= 1) ? kun[b][(rr - 1) * 7 + dx] * inv : 0.f;
        kern_pk[idx] = make_float2(v0, v1);
    }
}

// ---------- Stage C: channel mixing via bf16 MFMA, direct [c][pix] input ----------
__global__ __launch_bounds__(256) void gemm_mix(const ushortt* __restrict__ xfRe,
                                                const ushortt* __restrict__ xfIm,
                                                const float* __restrict__ wr,
                                                ushortt* __restrict__ mixRe,
                                                ushortt* __restrict__ mixIm) {
    __shared__ ushortt lA[2][5120];   // [o=128][k=32] stride 40 ushorts
    __shared__ uint32  lB[2][2560];   // [pix=128][k2=16(+4 pad)] dwords, swizzled
    int tid = threadIdx.x;
    int lane = tid & 63, wave = tid >> 6;
    int wm = wave >> 1, wn = wave & 1;
    int l15 = lane & 15, q4 = lane >> 4;
    int b = blockIdx.z >> 1, part = blockIdx.z & 1;
    const ushortt* Xb = (part ? xfIm : xfRe) + (size_t)b * (256 * HW)
                        + blockIdx.x * 128;
    ushortt* Dst = (part ? mixIm : mixRe) + (size_t)b * (256 * HW)
                   + (size_t)(blockIdx.y * 128) * HW + blockIdx.x * 128;
    const float* W = wr + (blockIdx.y * 128) * 256;

    int srow = tid >> 1, shalf = tid & 1;
    const float* wRow = W + srow * 256 + shalf * 16;
    int ldsOffA = srow * 40 + shalf * 16;

    int kt = tid >> 4;                 // 0..15
    int pq = tid & 15;                 // 0..15
    int kswz = kt ^ ((pq & 3) << 2);   // octet-bit XOR swizzle
    int rowbase = pq * 160;            // pq*8 rows * 20 dwords

    float4 wreg[4];
    uint4  a0, a1;
    #pragma unroll
    for (int i = 0; i < 4; ++i) wreg[i] = *(const float4*)(wRow + i * 4);
    {
        const ushortt* xp = Xb + (size_t)(2 * kt) * HW + pq * 8;
        a0 = *(const uint4*)xp;
        a1 = *(const uint4*)(xp + HW);
    }

    f32x4 acc[4][4];
    #pragma unroll
    for (int i = 0; i < 4; ++i)
        #pragma unroll
        for (int j = 0; j < 4; ++j)
            #pragma unroll
            for (int k = 0; k < 4; ++k) acc[i][j][k] = 0.f;

    int abase = (wm * 64 + l15) * 40 + q4 * 8;
    int baddr[4];
    #pragma unroll
    for (int f = 0; f < 4; ++f) {
        int pf = wn * 64 + f * 16 + l15;
        baddr[f] = pf * 40 + ((q4 ^ ((pf >> 3) & 3)) << 3);
    }

    for (int kb = 0; kb < 8; ++kb) {
        int bufc = kb & 1;
        {
            float ff[16] = {wreg[0].x, wreg[0].y, wreg[0].z, wreg[0].w,
                            wreg[1].x, wreg[1].y, wreg[1].z, wreg[1].w,
                            wreg[2].x, wreg[2].y, wreg[2].z, wreg[2].w,
                            wreg[3].x, wreg[3].y, wreg[3].z, wreg[3].w};
            uint32 p[8];
            #pragma unroll
            for (int j = 0; j < 8; ++j)
                p[j] = (uint32)f2bf(ff[2 * j]) | ((uint32)f2bf(ff[2 * j + 1]) << 16);
            *(uint4*)&lA[bufc][ldsOffA]     = make_uint4(p[0], p[1], p[2], p[3]);
            *(uint4*)&lA[bufc][ldsOffA + 8] = make_uint4(p[4], p[5], p[6], p[7]);
        }
        {
            uint32 d[8];
            d[0] = (a0.x & 0xffffu) | (a1.x << 16);
            d[1] = (a0.x >> 16)     | (a1.x & 0xffff0000u);
            d[2] = (a0.y & 0xffffu) | (a1.y << 16);
            d[3] = (a0.y >> 16)     | (a1.y & 0xffff0000u);
            d[4] = (a0.z & 0xffffu) | (a1.z << 16);
            d[5] = (a0.z >> 16)     | (a1.z & 0xffff0000u);
            d[6] = (a0.w & 0xffffu) | (a1.w << 16);
            d[7] = (a0.w >> 16)     | (a1.w & 0xffff0000u);
            uint32* lb = lB[bufc];
            #pragma unroll
            for (int j = 0; j < 8; ++j) lb[rowbase + j * 20 + kswz] = d[j];
        }
        __syncthreads();
        if (kb < 7) {
            const float* wN = wRow + (kb + 1) * 32;
            #pragma unroll
            for (int i = 0; i < 4; ++i) wreg[i] = *(const float4*)(wN + i * 4);
            const ushortt* xp = Xb + (size_t)((kb + 1) * 32 + 2 * kt) * HW + pq * 8;
            a0 = *(const uint4*)xp;
            a1 = *(const uint4*)(xp + HW);
        }
        short8 af[4], bf[4];
        const ushortt* lbU = (const ushortt*)lB[bufc];
        #pragma unroll
        for (int f = 0; f < 4; ++f) af[f] = *(const short8*)&lA[bufc][abase + f * 640];
        #pragma unroll
        for (int f = 0; f < 4; ++f) bf[f] = *(const short8*)&lbU[baddr[f]];
        #pragma unroll
        for (int fi = 0; fi < 4; ++fi)
            #pragma unroll
            for (int fj = 0; fj < 4; ++fj)
                acc[fi][fj] = __builtin_amdgcn_mfma_f32_16x16x32_bf16(
                    af[fi], bf[fj], acc[fi][fj], 0, 0, 0);
    }
    #pragma unroll
    for (int fi = 0; fi < 4; ++fi) {
        #pragma unroll
        for (int r = 0; r < 4; ++r) {
            int o_l = wm * 64 + fi * 16 + q4 * 4 + r;
            ushortt* dp = Dst + (size_t)o_l * HW + wn * 64 + l15;
            #pragma unroll
            for (int fj = 0; fj < 4; ++fj)
                dp[fj * 16] = f2bf(acc[fi][fj][r]);
        }
    }
}

// ---------- Stage D: 7x7 zero-padded conv, packed-fp32 dual-row FMA ----------
// acc2[j] = (out_row0[j], out_row1[j]); per input row dyy and tap col dx the
// sample broadcasts to both halves and the pre-paired taps (kern_pk) provide
// the (k[dyy][dx], k[dyy-1][dx]) 64-bit operand -> v_pk_fma_f32.
__global__ __launch_bounds__(256) void conv7(const ushortt* __restrict__ mixRe,
                                             const ushortt* __restrict__ mixIm,
                                             const float2* __restrict__ kern_pk,
                                             ushortt* __restrict__ outRe,
                                             ushortt* __restrict__ outIm) {
    __shared__ float tile[70 * 74];
    int b = blockIdx.z;
    int plane = blockIdx.y;
    int part = plane >> 8;
    size_t pbase = ((size_t)(b * 256 + (plane & 255))) << 14;
    const ushortt* src = (part ? mixIm : mixRe) + pbase;
    ushortt* dst = (part ? outIm : outRe) + pbase;
    int ty = (blockIdx.x >> 1) * 64, tx = (blockIdx.x & 1) * 64;
    int tid = threadIdx.x;
    const float2* kp = kern_pk + b * 56;

    // staging: 70 rows x 36 dwords (2 bf16 each), cols [tx-4, tx+68)
    // tile col t = gx - (tx-4): dword stores land on even float index (8B aligned)
    for (int idx = tid; idx < 2520; idx += 256) {
        int row = idx / 36, du = idx - row * 36;
        int gy = ty + row - 3, gx0 = tx - 4 + 2 * du;
        uint32 v = 0u;
        if ((unsigned)gy < 128u && (unsigned)gx0 < 128u)
            v = *(const uint32*)(src + gy * 128 + gx0);
        float2 w;
        w.x = __uint_as_float(v << 16);
        w.y = __uint_as_float(v & 0xffff0000u);
        *(float2*)&tile[row * 74 + 2 * du] = w;
    }
    __syncthreads();

    int ox = (tid & 7) * 8, oy = (tid >> 3) * 2;
    f32x2 acc2[8];
    #pragma unroll
    for (int j = 0; j < 8; ++j) { acc2[j].x = 0.f; acc2[j].y = 0.f; }

    #pragma unroll
    for (int dyy = 0; dyy < 8; ++dyy) {
        // out col ox+j uses tile col ox+j+dx+1 (tile col 0 == global tx-4)
        float row[14];
        #pragma unroll
        for (int m = 0; m < 14; ++m) row[m] = tile[(oy + dyy) * 74 + ox + 1 + m];
        #pragma unroll
        for (int dx = 0; dx < 7; ++dx) {
            float2 kl = kp[dyy * 7 + dx];          // uniform -> s_load_dwordx2
            f32x2 kk; kk.x = kl.x; kk.y = kl.y;
            #pragma unroll
            for (int j = 0; j < 8; ++j) {
                f32x2 rr; rr.x = row[dx + j]; rr.y = row[dx + j];
                acc2[j] = __builtin_elementwise_fma(rr, kk, acc2[j]);
            }
        }
    }

    uint32 s0[4], s1[4];
    #pragma unroll
    for (int m = 0; m < 4; ++m) {
        s0[m] = (uint32)f2bf(acc2[2 * m].x) | ((uint32)f2bf(acc2[2 * m + 1].x) << 16);
        s1[m] = (uint32)f2bf(acc2[2 * m].y) | ((uint32)f2bf(acc2[2 * m + 1].y) << 16);
    }
    *(uint4*)(dst + (ty + oy) * 128 + tx + ox)     = make_uint4(s0[0], s0[1], s0[2], s0[3]);
    *(uint4*)(dst + (ty + oy + 1) * 128 + tx + ox) = make_uint4(s1[0], s1[1], s1[2], s1[3]);
}

// ---------- Stage E: ifftshift + inverse FFT (conj trick) + residual add ----------
__global__ __launch_bounds__(1024) void ifft_add(const ushortt* __restrict__ convRe,
                                                 const ushortt* __restrict__ convIm,
                                                 const float* __restrict__ x,
                                                 float* __restrict__ out) {
    __shared__ float2 sc[128][129];
    __shared__ float twr[64], twi[64];
    int img = blockIdx.x;
    int tid = threadIdx.x, l = tid & 63, wv = tid >> 6;
    if (tid < 64) {
        float s, c;
        sincosf(-PIf * (float)tid / 64.0f, &s, &c);
        twr[tid] = c; twi[tid] = s;
    }
    const ushortt* cr = convRe + ((size_t)img << 14);
    const ushortt* ci = convIm + ((size_t)img << 14);
    __syncthreads();

    TwSet t = load_tw(twr, twi, l);
    bool u8 = (l & 8) != 0, u4 = (l & 4) != 0, u2 = (l & 2) != 0, u1 = (l & 1) != 0;
    int e = brev6(l);

    // row pass: ifftshift gather from global (conj), pair-swap FFT, LDS natural
    {
        int p0 = ((wv * 8) + 64) & 127;
        float nar = bf2f(cr[p0 * 128 + 64 + l]), nai = bf2f(ci[p0 * 128 + 64 + l]);
        float nbr = bf2f(cr[p0 * 128 + l]),      nbi = bf2f(ci[p0 * 128 + l]);
        for (int r = 0; r < 8; ++r) {
            int u = wv * 8 + r;
            float Ar = nar, Ai = -nai, Br = nbr, Bi = -nbi;
            if (r < 7) {
                int p = ((u + 1) + 64) & 127;
                nar = bf2f(cr[p * 128 + 64 + l]); nai = bf2f(ci[p * 128 + 64 + l]);
                nbr = bf2f(cr[p * 128 + l]);      nbi = bf2f(ci[p * 128 + l]);
            }
            fft128_ps(Ar, Ai, Br, Bi, t, u8, u4, u2, u1);
            sc[u][e]      = make_float2(Ar, Ai);
            sc[u][e + 64] = make_float2(Br, Bi);
        }
    }
    __syncthreads();

    // column pass
    for (int r = 0; r < 8; ++r) {
        int c = wv * 8 + r;
        float2 va = sc[l][c], vbv = sc[l + 64][c];
        float Ar = va.x, Ai = va.y, Br = vbv.x, Bi = vbv.y;
        fft128_ps(Ar, Ai, Br, Bi, t, u8, u4, u2, u1);
        sc[e][c]      = make_float2(Ar, Ai);
        sc[e + 64][c] = make_float2(Br, Bi);
    }
    __syncthreads();

    const float* xi = x + (size_t)img * HW;
    float* oo = out + (size_t)img * HW;
    for (int idx2 = tid; idx2 < 8192; idx2 += 1024) {
        int y = idx2 >> 6, xp = (idx2 & 63) * 2;
        float r0 = sc[y][xp].x     * (1.0f / 128.0f);
        float r1 = sc[y][xp + 1].x * (1.0f / 128.0f);
        float2 xv = *(const float2*)(xi + y * 128 + xp);
        float2 ov; ov.x = r0 + xv.x; ov.y = r1 + xv.y;
        *(float2*)(oo + y * 128 + xp) = ov;
    }
}

extern "C" void kernel_launch(void* const* d_in, const int* in_sizes, int n_in,
                              void* d_out, int out_size, void* d_ws, size_t ws_size,
                              hipStream_t stream) {
    const float* x  = (const float*)d_in[0];
    const float* w1 = (const float*)d_in[1];
    const float* b1 = (const float*)d_in[2];
    const float* w2 = (const float*)d_in[3];
    const float* b2 = (const float*)d_in[4];
    const float* wr = (const float*)d_in[5];

    char* ws = (char*)d_ws;
    ushortt* xfRe  = (ushortt*)ws;                       // 64 MiB
    ushortt* xfIm  = xfRe + 33554432;                    // 64 MiB
    ushortt* mixRe = (ushortt*)(ws + 134217728);         // 64 MiB (separate: gemm in != out)
    ushortt* mixIm = mixRe + 33554432;                   // 64 MiB
    ushortt* convRe = xfRe, *convIm = xfIm;              // aliases (xf dead after gemm)
    float* magc = (float*)(ws + 268435456);
    float2* kern_pk = (float2*)(ws + 268435456 + 2048);  // 448 float2 = 3584 B

    hipMemsetAsync(magc, 0, 392 * sizeof(float), stream);
    fft_fwd<<<2048, 1024, 0, stream>>>(x, xfRe, xfIm, magc);
    mlp_kern<<<1, 256, 0, stream>>>(magc, w1, b1, w2, b2, kern_pk);
    gemm_mix<<<dim3(128, 2, 16), 256, 0, stream>>>(xfRe, xfIm, wr, mixRe, mixIm);
    conv7<<<dim3(4, 512, 8), 256, 0, stream>>>(mixRe, mixIm, kern_pk, convRe, convIm);
    ifft_add<<<2048, 1024, 0, stream>>>(convRe, convIm, x, (float*)d_out);
}

// Round 6
// 579.204 us; speedup vs baseline: 1.3155x; 1.0286x over previous
//
#include <hip/hip_runtime.h>

#define HW 16384
#define PIf 3.14159265358979323846f
typedef unsigned short ushortt;
typedef unsigned int uint32;
typedef __attribute__((ext_vector_type(8))) short short8;
typedef __attribute__((ext_vector_type(4))) float f32x4;
typedef __attribute__((ext_vector_type(2))) float f32x2;
typedef __attribute__((ext_vector_type(2))) unsigned int uintv2;

// ---------- bf16 raw helpers ----------
__device__ __forceinline__ float bf2f(ushortt b) {
    return __uint_as_float(((unsigned)b) << 16);
}
__device__ __forceinline__ ushortt f2bf(float f) {
    unsigned u = __float_as_uint(f);
    u += 0x7fffu + ((u >> 16) & 1u);   // RNE
    return (ushortt)(u >> 16);
}
__device__ __forceinline__ int brev6(int v) { return (int)(__brev((unsigned)v) >> 26); }

// ---------- butterfly: (A,B) -> (A+B, (A-B)*t) ----------
__device__ __forceinline__ void bfly(float& Ar, float& Ai, float& Br, float& Bi,
                                     float tr, float ti) {
    float sr = Ar + Br, si = Ai + Bi;
    float dr = Ar - Br, di = Ai - Bi;
    Ar = sr; Ai = si;
    Br = dr * tr - di * ti;
    Bi = dr * ti + di * tr;
}

// ---------- cross-lane re-pairing swaps ----------
__device__ __forceinline__ void xswap32(float& a, float& b) {
    uintv2 r = __builtin_amdgcn_permlane32_swap(__float_as_uint(a), __float_as_uint(b), false, false);
    a = __uint_as_float(r.x); b = __uint_as_float(r.y);
}
__device__ __forceinline__ void xswap16(float& a, float& b) {
    uintv2 r = __builtin_amdgcn_permlane16_swap(__float_as_uint(a), __float_as_uint(b), false, false);
    a = __uint_as_float(r.x); b = __uint_as_float(r.y);
}
template<int IMM>
__device__ __forceinline__ void pswap_sw(float& a, float& b, bool up) {
    float sel = up ? a : b;
    float rcv = __int_as_float(__builtin_amdgcn_ds_swizzle(__float_as_int(sel), IMM));
    a = up ? rcv : a;
    b = up ? b : rcv;
}
template<int CTRL>
__device__ __forceinline__ void pswap_dpp(float& a, float& b, bool up) {
    float sel = up ? a : b;
    float rcv = __int_as_float(__builtin_amdgcn_update_dpp(0, __float_as_int(sel), CTRL, 0xF, 0xF, true));
    a = up ? rcv : a;
    b = up ? b : rcv;
}

struct TwSet { float r0,i0,r1,i1,r2,i2,r3,i3,r4,i4,r5,i5; };

__device__ __forceinline__ TwSet load_tw(const float* __restrict__ twr,
                                         const float* __restrict__ twi, int l) {
    TwSet t;
    t.r0 = twr[l];            t.i0 = twi[l];
    t.r1 = twr[(l & 31) << 1]; t.i1 = twi[(l & 31) << 1];
    t.r2 = twr[(l & 15) << 2]; t.i2 = twi[(l & 15) << 2];
    t.r3 = twr[(l & 7)  << 3]; t.i3 = twi[(l & 7)  << 3];
    t.r4 = twr[(l & 3)  << 4]; t.i4 = twi[(l & 3)  << 4];
    t.r5 = twr[(l & 1)  << 5]; t.i5 = twi[(l & 1)  << 5];
    return t;
}

// ---------- pair-swap 128-pt DIF FFT, 2 complex/lane ----------
// In: lane l holds A=z[l], B=z[l+64]. Out: A=Z[brev6(l)], B=Z[brev6(l)+64].
__device__ __forceinline__ void fft128_ps(float& Ar, float& Ai, float& Br, float& Bi,
                                          const TwSet& t,
                                          bool u8, bool u4, bool u2, bool u1) {
    bfly(Ar, Ai, Br, Bi, t.r0, t.i0);                       // d=64 (in-register)
    xswap32(Ar, Br); xswap32(Ai, Bi);
    bfly(Ar, Ai, Br, Bi, t.r1, t.i1);                       // d=32 (VALU permlane)
    xswap16(Ar, Br); xswap16(Ai, Bi);
    bfly(Ar, Ai, Br, Bi, t.r2, t.i2);                       // d=16 (VALU permlane)
    pswap_sw<0x201F>(Ar, Br, u8); pswap_sw<0x201F>(Ai, Bi, u8);
    bfly(Ar, Ai, Br, Bi, t.r3, t.i3);                       // d=8  (ds_swizzle)
    pswap_sw<0x101F>(Ar, Br, u4); pswap_sw<0x101F>(Ai, Bi, u4);
    bfly(Ar, Ai, Br, Bi, t.r4, t.i4);                       // d=4  (ds_swizzle)
    pswap_dpp<0x4E>(Ar, Br, u2); pswap_dpp<0x4E>(Ai, Bi, u2);
    bfly(Ar, Ai, Br, Bi, t.r5, t.i5);                       // d=2  (DPP)
    pswap_dpp<0xB1>(Ar, Br, u1); pswap_dpp<0xB1>(Ai, Bi, u1);
    {   // d=1, tw = 1
        float sr = Ar + Br, si = Ai + Bi;
        float dr = Ar - Br, di = Ai - Bi;
        Ar = sr; Ai = si; Br = dr; Bi = di;
    }
}

// ---------- Stage A: forward FFT (real-packed rows) + fftshift + central-mag ----------
// Row pass: z = row(2p) + i*row(2p+1) -> 4 pair-FFTs/wave (halved).
// Col pass: unpack X0/X1 from Z symmetry during LDS read; 1/2 folded into 1/256 scale.
__global__ __launch_bounds__(1024) void fft_fwd(const float* __restrict__ x,
                                                ushortt* __restrict__ xfRe,
                                                ushortt* __restrict__ xfIm,
                                                float* __restrict__ magc) {
    __shared__ float2 sc[128][129];
    __shared__ float twr[64], twi[64];
    int img = blockIdx.x;
    int tid = threadIdx.x, l = tid & 63, wv = tid >> 6;
    if (tid < 64) {
        float s, c;
        sincosf(-PIf * (float)tid / 64.0f, &s, &c);
        twr[tid] = c; twi[tid] = s;
    }
    const float* xi = x + (size_t)img * HW;
    __syncthreads();

    TwSet t = load_tw(twr, twi, l);
    bool u8 = (l & 8) != 0, u4 = (l & 4) != 0, u2 = (l & 2) != 0, u1 = (l & 1) != 0;
    int e = brev6(l);

    // ---- row pass: all loads issued upfront (latency hiding), 4 pair-FFTs
    float lar[4], lai[4], lbr[4], lbi[4];
    #pragma unroll
    for (int r = 0; r < 4; ++r) {
        int p = wv * 4 + r;
        lar[r] = xi[(2 * p) * 128 + l];
        lai[r] = xi[(2 * p + 1) * 128 + l];
        lbr[r] = xi[(2 * p) * 128 + 64 + l];
        lbi[r] = xi[(2 * p + 1) * 128 + 64 + l];
    }
    #pragma unroll
    for (int r = 0; r < 4; ++r) {
        int p = wv * 4 + r;
        float Ar = lar[r], Ai = lai[r], Br = lbr[r], Bi = lbi[r];
        fft128_ps(Ar, Ai, Br, Bi, t, u8, u4, u2, u1);
        sc[p][e]      = make_float2(Ar, Ai);   // Z_p natural order, rows 0..63
        sc[p][e + 64] = make_float2(Br, Bi);
    }
    __syncthreads();

    // ---- col pass: unpack rows from Z symmetry, FFT, stage in regs
    float oar[8], oai[8], obr[8], obi[8];
    int pa = l >> 1, pb = 32 + (l >> 1);
    bool odd = (l & 1) != 0;
    #pragma unroll
    for (int r = 0; r < 8; ++r) {
        int c = wv * 8 + r, cm = (128 - c) & 127;
        float2 Za = sc[pa][c], Zma = sc[pa][cm];
        float2 Zb = sc[pb][c], Zmb = sc[pb][cm];
        // X(2q)[c] = Zr+Zmr, Zi-Zmi ; X(2q+1)[c] = Zi+Zmi, Zmr-Zr   (x2, folded)
        float Ar = odd ? (Za.y + Zma.y) : (Za.x + Zma.x);
        float Ai = odd ? (Zma.x - Za.x) : (Za.y - Zma.y);
        float Br = odd ? (Zb.y + Zmb.y) : (Zb.x + Zmb.x);
        float Bi = odd ? (Zmb.x - Zb.x) : (Zb.y - Zmb.y);
        fft128_ps(Ar, Ai, Br, Bi, t, u8, u4, u2, u1);
        oar[r] = Ar; oai[r] = Ai; obr[r] = Br; obi[r] = Bi;
    }
    __syncthreads();
    #pragma unroll
    for (int r = 0; r < 8; ++r) {
        int c = wv * 8 + r;
        sc[e][c]      = make_float2(oar[r], oai[r]);
        sc[e + 64][c] = make_float2(obr[r], obi[r]);
    }
    __syncthreads();

    // coalesced fftshift'd bf16 write (ortho 1/128, plus 1/2 unpack fold -> 1/256)
    uint32* oRe = (uint32*)(xfRe + ((size_t)img << 14));
    uint32* oIm = (uint32*)(xfIm + ((size_t)img << 14));
    for (int idx2 = tid; idx2 < 8192; idx2 += 1024) {
        int p = idx2 >> 6, qp = idx2 & 63, q = qp * 2;
        int u  = (p + 64) & 127;
        int v0 = (q + 64) & 127;          // even, pair contiguous
        const float scl = 1.0f / 256.0f;
        float2 e0 = sc[u][v0], e1 = sc[u][v0 + 1];
        uint32 re = (uint32)f2bf(e0.x * scl) | ((uint32)f2bf(e1.x * scl) << 16);
        uint32 im = (uint32)f2bf(e0.y * scl) | ((uint32)f2bf(e1.y * scl) << 16);
        oRe[p * 64 + qp] = re;
        oIm[p * 64 + qp] = im;
    }
    // central 7x7 |xf| accumulation (fp32)
    if (tid < 49) {
        int p = 61 + tid / 7, q = 61 + tid % 7;
        int u = (p + 64) & 127, v = (q + 64) & 127;
        float2 z = sc[u][v];
        float mag = sqrtf(z.x * z.x + z.y * z.y) * (1.0f / 256.0f);
        atomicAdd(&magc[(img >> 8) * 49 + tid], mag);
    }
}

// ---------- Stage B: tiny MLP + anisotropic kernel build (pre-paired taps) ----------
__global__ __launch_bounds__(256) void mlp_kern(const float* __restrict__ magc,
                                                const float* __restrict__ w1,
                                                const float* __restrict__ b1,
                                                const float* __restrict__ w2,
                                                const float* __restrict__ b2,
                                                float2* __restrict__ kern_pk) {
    __shared__ float hid[8][32];
    __shared__ float par[8][3];
    __shared__ float kun[8][49];
    __shared__ float ksum[8];
    int tid = threadIdx.x;
    {
        int b = tid >> 5, n = tid & 31;
        float acc = b1[n];
        for (int i = 0; i < 49; ++i)
            acc = fmaf(magc[b * 49 + i] * (1.0f / 256.0f), w1[i * 32 + n], acc);
        hid[b][n] = fmaxf(acc, 0.f);
    }
    __syncthreads();
    if (tid < 24) {
        int b = tid / 3, j = tid % 3;
        float acc = b2[j];
        for (int n = 0; n < 32; ++n) acc = fmaf(hid[b][n], w2[n * 3 + j], acc);
        par[b][j] = acc;
    }
    __syncthreads();
    for (int idx = tid; idx < 392; idx += 256) {
        int b = idx / 49, ij = idx % 49;
        int i = ij / 7, j2 = ij % 7;
        float p0 = par[b][0], p1 = par[b][1], p2 = par[b][2];
        float theta = atan2f(p0, p1) * 0.5f + PIf * 0.5f;
        float lam1 = expf(p2);
        float lam2 = 1.0f / (lam1 + 1e-8f);
        float yy = (float)(i - 3), xx = (float)(j2 - 3);
        float ct, st;
        sincosf(theta, &st, &ct);
        float xr =  xx * ct + yy * st;
        float yr = -xx * st + yy * ct;
        kun[b][ij] = expf(-(xr * xr / (2.f * lam1 * lam1) + yr * yr / (2.f * lam2 * lam2)));
    }
    __syncthreads();
    if (tid < 8) {
        float s = 0.f;
        for (int t = 0; t < 49; ++t) s += kun[tid][t];
        ksum[tid] = s + 1e-8f;
    }
    __syncthreads();
    for (int idx = tid; idx < 448; idx += 256) {
        int b  = idx / 56;
        int r7 = idx - b * 56;
        int rr = r7 / 7, dx = r7 - rr * 7;
        float inv = 1.0f / ksum[b];
        float v0 = (rr < 7)  ? kun[b][rr * 7 + dx] * inv       : 0.f;
        float v1 = (rr >= 1) ? kun[b][(rr - 1) * 7 + dx] * inv : 0.f;
        kern_pk[idx] = make_float2(v0, v1);
    }
}

// ---------- Stage C: channel mixing via bf16 MFMA, direct [c][pix] input ----------
__global__ __launch_bounds__(256) void gemm_mix(const ushortt* __restrict__ xfRe,
                                                const ushortt* __restrict__ xfIm,
                                                const float* __restrict__ wr,
                                                ushortt* __restrict__ mixRe,
                                                ushortt* __restrict__ mixIm) {
    __shared__ ushortt lA[2][5120];   // [o=128][k=32] stride 40 ushorts
    __shared__ uint32  lB[2][2560];   // [pix=128][k2=16(+4 pad)] dwords, swizzled
    int tid = threadIdx.x;
    int lane = tid & 63, wave = tid >> 6;
    int wm = wave >> 1, wn = wave & 1;
    int l15 = lane & 15, q4 = lane >> 4;
    int b = blockIdx.z >> 1, part = blockIdx.z & 1;
    const ushortt* Xb = (part ? xfIm : xfRe) + (size_t)b * (256 * HW)
                        + blockIdx.x * 128;
    ushortt* Dst = (part ? mixIm : mixRe) + (size_t)b * (256 * HW)
                   + (size_t)(blockIdx.y * 128) * HW + blockIdx.x * 128;
    const float* W = wr + (blockIdx.y * 128) * 256;

    int srow = tid >> 1, shalf = tid & 1;
    const float* wRow = W + srow * 256 + shalf * 16;
    int ldsOffA = srow * 40 + shalf * 16;

    int kt = tid >> 4;                 // 0..15
    int pq = tid & 15;                 // 0..15
    int kswz = kt ^ ((pq & 3) << 2);   // octet-bit XOR swizzle
    int rowbase = pq * 160;            // pq*8 rows * 20 dwords

    float4 wreg[4];
    uint4  a0, a1;
    #pragma unroll
    for (int i = 0; i < 4; ++i) wreg[i] = *(const float4*)(wRow + i * 4);
    {
        const ushortt* xp = Xb + (size_t)(2 * kt) * HW + pq * 8;
        a0 = *(const uint4*)xp;
        a1 = *(const uint4*)(xp + HW);
    }

    f32x4 acc[4][4];
    #pragma unroll
    for (int i = 0; i < 4; ++i)
        #pragma unroll
        for (int j = 0; j < 4; ++j)
            #pragma unroll
            for (int k = 0; k < 4; ++k) acc[i][j][k] = 0.f;

    int abase = (wm * 64 + l15) * 40 + q4 * 8;
    int baddr[4];
    #pragma unroll
    for (int f = 0; f < 4; ++f) {
        int pf = wn * 64 + f * 16 + l15;
        baddr[f] = pf * 40 + ((q4 ^ ((pf >> 3) & 3)) << 3);
    }

    for (int kb = 0; kb < 8; ++kb) {
        int bufc = kb & 1;
        {
            float ff[16] = {wreg[0].x, wreg[0].y, wreg[0].z, wreg[0].w,
                            wreg[1].x, wreg[1].y, wreg[1].z, wreg[1].w,
                            wreg[2].x, wreg[2].y, wreg[2].z, wreg[2].w,
                            wreg[3].x, wreg[3].y, wreg[3].z, wreg[3].w};
            uint32 p[8];
            #pragma unroll
            for (int j = 0; j < 8; ++j)
                p[j] = (uint32)f2bf(ff[2 * j]) | ((uint32)f2bf(ff[2 * j + 1]) << 16);
            *(uint4*)&lA[bufc][ldsOffA]     = make_uint4(p[0], p[1], p[2], p[3]);
            *(uint4*)&lA[bufc][ldsOffA + 8] = make_uint4(p[4], p[5], p[6], p[7]);
        }
        {
            uint32 d[8];
            d[0] = (a0.x & 0xffffu) | (a1.x << 16);
            d[1] = (a0.x >> 16)     | (a1.x & 0xffff0000u);
            d[2] = (a0.y & 0xffffu) | (a1.y << 16);
            d[3] = (a0.y >> 16)     | (a1.y & 0xffff0000u);
            d[4] = (a0.z & 0xffffu) | (a1.z << 16);
            d[5] = (a0.z >> 16)     | (a1.z & 0xffff0000u);
            d[6] = (a0.w & 0xffffu) | (a1.w << 16);
            d[7] = (a0.w >> 16)     | (a1.w & 0xffff0000u);
            uint32* lb = lB[bufc];
            #pragma unroll
            for (int j = 0; j < 8; ++j) lb[rowbase + j * 20 + kswz] = d[j];
        }
        __syncthreads();
        if (kb < 7) {
            const float* wN = wRow + (kb + 1) * 32;
            #pragma unroll
            for (int i = 0; i < 4; ++i) wreg[i] = *(const float4*)(wN + i * 4);
            const ushortt* xp = Xb + (size_t)((kb + 1) * 32 + 2 * kt) * HW + pq * 8;
            a0 = *(const uint4*)xp;
            a1 = *(const uint4*)(xp + HW);
        }
        short8 af[4], bf[4];
        const ushortt* lbU = (const ushortt*)lB[bufc];
        #pragma unroll
        for (int f = 0; f < 4; ++f) af[f] = *(const short8*)&lA[bufc][abase + f * 640];
        #pragma unroll
        for (int f = 0; f < 4; ++f) bf[f] = *(const short8*)&lbU[baddr[f]];
        #pragma unroll
        for (int fi = 0; fi < 4; ++fi)
            #pragma unroll
            for (int fj = 0; fj < 4; ++fj)
                acc[fi][fj] = __builtin_amdgcn_mfma_f32_16x16x32_bf16(
                    af[fi], bf[fj], acc[fi][fj], 0, 0, 0);
    }
    #pragma unroll
    for (int fi = 0; fi < 4; ++fi) {
        #pragma unroll
        for (int r = 0; r < 4; ++r) {
            int o_l = wm * 64 + fi * 16 + q4 * 4 + r;
            ushortt* dp = Dst + (size_t)o_l * HW + wn * 64 + l15;
            #pragma unroll
            for (int fj = 0; fj < 4; ++fj)
                dp[fj * 16] = f2bf(acc[fi][fj][r]);
        }
    }
}

// ---------- Stage D: 7x7 zero-padded conv, packed-fp32 dual-row FMA ----------
__global__ __launch_bounds__(256) void conv7(const ushortt* __restrict__ mixRe,
                                             const ushortt* __restrict__ mixIm,
                                             const float2* __restrict__ kern_pk,
                                             ushortt* __restrict__ outRe,
                                             ushortt* __restrict__ outIm) {
    __shared__ float tile[70 * 74];
    int b = blockIdx.z;
    int plane = blockIdx.y;
    int part = plane >> 8;
    size_t pbase = ((size_t)(b * 256 + (plane & 255))) << 14;
    const ushortt* src = (part ? mixIm : mixRe) + pbase;
    ushortt* dst = (part ? outIm : outRe) + pbase;
    int ty = (blockIdx.x >> 1) * 64, tx = (blockIdx.x & 1) * 64;
    int tid = threadIdx.x;
    const float2* kp = kern_pk + b * 56;

    for (int idx = tid; idx < 2520; idx += 256) {
        int row = idx / 36, du = idx - row * 36;
        int gy = ty + row - 3, gx0 = tx - 4 + 2 * du;
        uint32 v = 0u;
        if ((unsigned)gy < 128u && (unsigned)gx0 < 128u)
            v = *(const uint32*)(src + gy * 128 + gx0);
        float2 w;
        w.x = __uint_as_float(v << 16);
        w.y = __uint_as_float(v & 0xffff0000u);
        *(float2*)&tile[row * 74 + 2 * du] = w;
    }
    __syncthreads();

    int ox = (tid & 7) * 8, oy = (tid >> 3) * 2;
    f32x2 acc2[8];
    #pragma unroll
    for (int j = 0; j < 8; ++j) { acc2[j].x = 0.f; acc2[j].y = 0.f; }

    #pragma unroll
    for (int dyy = 0; dyy < 8; ++dyy) {
        float row[14];
        #pragma unroll
        for (int m = 0; m < 14; ++m) row[m] = tile[(oy + dyy) * 74 + ox + 1 + m];
        #pragma unroll
        for (int dx = 0; dx < 7; ++dx) {
            float2 kl = kp[dyy * 7 + dx];
            f32x2 kk; kk.x = kl.x; kk.y = kl.y;
            #pragma unroll
            for (int j = 0; j < 8; ++j) {
                f32x2 rr; rr.x = row[dx + j]; rr.y = row[dx + j];
                acc2[j] = __builtin_elementwise_fma(rr, kk, acc2[j]);
            }
        }
    }

    uint32 s0[4], s1[4];
    #pragma unroll
    for (int m = 0; m < 4; ++m) {
        s0[m] = (uint32)f2bf(acc2[2 * m].x) | ((uint32)f2bf(acc2[2 * m + 1].x) << 16);
        s1[m] = (uint32)f2bf(acc2[2 * m].y) | ((uint32)f2bf(acc2[2 * m + 1].y) << 16);
    }
    *(uint4*)(dst + (ty + oy) * 128 + tx + ox)     = make_uint4(s0[0], s0[1], s0[2], s0[3]);
    *(uint4*)(dst + (ty + oy + 1) * 128 + tx + ox) = make_uint4(s1[0], s1[1], s1[2], s1[3]);
}

// ---------- Stage E: ifftshift + IFFT (conj trick, paired real-output cols) + x ----------
// Row pass: full complex (conj'd), loads upfront. Col pass: two columns per FFT via
// z = (F0 + conj(F0∘rev)) + i(F1 + conj(F1∘rev)) -> fft(z) = Re(out0) + i*Re(out1).
__global__ __launch_bounds__(1024) void ifft_add(const ushortt* __restrict__ convRe,
                                                 const ushortt* __restrict__ convIm,
                                                 const float* __restrict__ x,
                                                 float* __restrict__ out) {
    __shared__ float2 sc[128][129];
    __shared__ float twr[64], twi[64];
    int img = blockIdx.x;
    int tid = threadIdx.x, l = tid & 63, wv = tid >> 6;
    if (tid < 64) {
        float s, c;
        sincosf(-PIf * (float)tid / 64.0f, &s, &c);
        twr[tid] = c; twi[tid] = s;
    }
    const ushortt* cr = convRe + ((size_t)img << 14);
    const ushortt* ci = convIm + ((size_t)img << 14);
    __syncthreads();

    TwSet t = load_tw(twr, twi, l);
    bool u8 = (l & 8) != 0, u4 = (l & 4) != 0, u2 = (l & 2) != 0, u1 = (l & 1) != 0;
    int e = brev6(l);

    // ---- row pass: ifftshift gather (conj), ALL loads upfront, 8 FFTs
    {
        float nar[8], nai[8], nbr[8], nbi[8];
        #pragma unroll
        for (int r = 0; r < 8; ++r) {
            int p = ((wv * 8 + r) + 64) & 127;
            nar[r] = bf2f(cr[p * 128 + 64 + l]);
            nai[r] = bf2f(ci[p * 128 + 64 + l]);
            nbr[r] = bf2f(cr[p * 128 + l]);
            nbi[r] = bf2f(ci[p * 128 + l]);
        }
        #pragma unroll
        for (int r = 0; r < 8; ++r) {
            int u = wv * 8 + r;
            float Ar = nar[r], Ai = -nai[r], Br = nbr[r], Bi = -nbi[r];
            fft128_ps(Ar, Ai, Br, Bi, t, u8, u4, u2, u1);
            sc[u][e]      = make_float2(Ar, Ai);
            sc[u][e + 64] = make_float2(Br, Bi);
        }
    }
    __syncthreads();

    // ---- col pass: 4 column-PAIR FFTs per wave, staged in regs
    float oar[4], oai[4], obr[4], obi[4];
    int rv  = (128 - l) & 127;       // reverse of row l
    int rv2 = (64 - l) & 127;        // reverse of row l+64
    #pragma unroll
    for (int r = 0; r < 4; ++r) {
        int m = wv * 4 + r;
        int c0 = 2 * m, c1 = 2 * m + 1;
        float2 P  = sc[l][c0],      R  = sc[l][c1];
        float2 Q  = sc[rv][c0],     S  = sc[rv][c1];
        float2 P2 = sc[l + 64][c0], R2 = sc[l + 64][c1];
        float2 Q2 = sc[rv2][c0],    S2 = sc[rv2][c1];
        float Ar = P.x + Q.x - R.y + S.y;
        float Ai = P.y - Q.y + R.x + S.x;
        float Br = P2.x + Q2.x - R2.y + S2.y;
        float Bi = P2.y - Q2.y + R2.x + S2.x;
        fft128_ps(Ar, Ai, Br, Bi, t, u8, u4, u2, u1);
        oar[r] = Ar; oai[r] = Ai; obr[r] = Br; obi[r] = Bi;
    }
    __syncthreads();
    #pragma unroll
    for (int r = 0; r < 4; ++r) {
        int m = wv * 4 + r;
        sc[e][m]      = make_float2(oar[r], oai[r]);   // (.x=col 2m, .y=col 2m+1)
        sc[e + 64][m] = make_float2(obr[r], obi[r]);
    }
    __syncthreads();

    // ---- output: slot m -> columns (2m, 2m+1); scale 1/256 (conj-trick 1/128 * pack 1/2)
    const float* xi = x + (size_t)img * HW;
    float* oo = out + (size_t)img * HW;
    for (int idx2 = tid; idx2 < 8192; idx2 += 1024) {
        int y = idx2 >> 6, m = idx2 & 63;
        float2 v = sc[y][m];
        float2 xv = *(const float2*)(xi + y * 128 + 2 * m);
        float2 ov;
        ov.x = v.x * (1.0f / 256.0f) + xv.x;
        ov.y = v.y * (1.0f / 256.0f) + xv.y;
        *(float2*)(oo + y * 128 + 2 * m) = ov;
    }
}

extern "C" void kernel_launch(void* const* d_in, const int* in_sizes, int n_in,
                              void* d_out, int out_size, void* d_ws, size_t ws_size,
                              hipStream_t stream) {
    const float* x  = (const float*)d_in[0];
    const float* w1 = (const float*)d_in[1];
    const float* b1 = (const float*)d_in[2];
    const float* w2 = (const float*)d_in[3];
    const float* b2 = (const float*)d_in[4];
    const float* wr = (const float*)d_in[5];

    char* ws = (char*)d_ws;
    ushortt* xfRe  = (ushortt*)ws;                       // 64 MiB
    ushortt* xfIm  = xfRe + 33554432;                    // 64 MiB
    ushortt* mixRe = (ushortt*)(ws + 134217728);         // 64 MiB (separate: gemm in != out)
    ushortt* mixIm = mixRe + 33554432;                   // 64 MiB
    ushortt* convRe = xfRe, *convIm = xfIm;              // aliases (xf dead after gemm)
    float* magc = (float*)(ws + 268435456);
    float2* kern_pk = (float2*)(ws + 268435456 + 2048);  // 448 float2 = 3584 B

    hipMemsetAsync(magc, 0, 392 * sizeof(float), stream);
    fft_fwd<<<2048, 1024, 0, stream>>>(x, xfRe, xfIm, magc);
    mlp_kern<<<1, 256, 0, stream>>>(magc, w1, b1, w2, b2, kern_pk);
    gemm_mix<<<dim3(128, 2, 16), 256, 0, stream>>>(xfRe, xfIm, wr, mixRe, mixIm);
    conv7<<<dim3(4, 512, 8), 256, 0, stream>>>(mixRe, mixIm, kern_pk, convRe, convIm);
    ifft_add<<<2048, 1024, 0, stream>>>(convRe, convIm, x, (float*)d_out);
}

// Round 7
// 562.240 us; speedup vs baseline: 1.3551x; 1.0302x over previous
//
#include <hip/hip_runtime.h>

#define HW 16384
#define PIf 3.14159265358979323846f
typedef unsigned short ushortt;
typedef unsigned int uint32;
typedef __attribute__((ext_vector_type(8))) short short8;
typedef __attribute__((ext_vector_type(4))) float f32x4;
typedef __attribute__((ext_vector_type(2))) float f32x2;
typedef __attribute__((ext_vector_type(2))) unsigned int uintv2;

// ---------- bf16 raw helpers ----------
__device__ __forceinline__ float bf2f(ushortt b) {
    return __uint_as_float(((unsigned)b) << 16);
}
__device__ __forceinline__ ushortt f2bf(float f) {
    unsigned u = __float_as_uint(f);
    u += 0x7fffu + ((u >> 16) & 1u);   // RNE
    return (ushortt)(u >> 16);
}
__device__ __forceinline__ int brev6(int v) { return (int)(__brev((unsigned)v) >> 26); }

// ---------- butterfly: (A,B) -> (A+B, (A-B)*t) ----------
__device__ __forceinline__ void bfly(float& Ar, float& Ai, float& Br, float& Bi,
                                     float tr, float ti) {
    float sr = Ar + Br, si = Ai + Bi;
    float dr = Ar - Br, di = Ai - Bi;
    Ar = sr; Ai = si;
    Br = dr * tr - di * ti;
    Bi = dr * ti + di * tr;
}

// ---------- cross-lane re-pairing swaps ----------
__device__ __forceinline__ void xswap32(float& a, float& b) {
    uintv2 r = __builtin_amdgcn_permlane32_swap(__float_as_uint(a), __float_as_uint(b), false, false);
    a = __uint_as_float(r.x); b = __uint_as_float(r.y);
}
__device__ __forceinline__ void xswap16(float& a, float& b) {
    uintv2 r = __builtin_amdgcn_permlane16_swap(__float_as_uint(a), __float_as_uint(b), false, false);
    a = __uint_as_float(r.x); b = __uint_as_float(r.y);
}
template<int IMM>
__device__ __forceinline__ void pswap_sw(float& a, float& b, bool up) {
    float sel = up ? a : b;
    float rcv = __int_as_float(__builtin_amdgcn_ds_swizzle(__float_as_int(sel), IMM));
    a = up ? rcv : a;
    b = up ? b : rcv;
}
template<int CTRL>
__device__ __forceinline__ void pswap_dpp(float& a, float& b, bool up) {
    float sel = up ? a : b;
    float rcv = __int_as_float(__builtin_amdgcn_update_dpp(0, __float_as_int(sel), CTRL, 0xF, 0xF, true));
    a = up ? rcv : a;
    b = up ? b : rcv;
}

struct TwSet { float r0,i0,r1,i1,r2,i2,r3,i3,r4,i4,r5,i5; };

__device__ __forceinline__ TwSet load_tw(const float* __restrict__ twr,
                                         const float* __restrict__ twi, int l) {
    TwSet t;
    t.r0 = twr[l];            t.i0 = twi[l];
    t.r1 = twr[(l & 31) << 1]; t.i1 = twi[(l & 31) << 1];
    t.r2 = twr[(l & 15) << 2]; t.i2 = twi[(l & 15) << 2];
    t.r3 = twr[(l & 7)  << 3]; t.i3 = twi[(l & 7)  << 3];
    t.r4 = twr[(l & 3)  << 4]; t.i4 = twi[(l & 3)  << 4];
    t.r5 = twr[(l & 1)  << 5]; t.i5 = twi[(l & 1)  << 5];
    return t;
}

// ---------- pair-swap 128-pt DIF FFT, 2 complex/lane ----------
// In: lane l holds A=z[l], B=z[l+64]. Out: A=Z[brev6(l)], B=Z[brev6(l)+64].
__device__ __forceinline__ void fft128_ps(float& Ar, float& Ai, float& Br, float& Bi,
                                          const TwSet& t,
                                          bool u8, bool u4, bool u2, bool u1) {
    bfly(Ar, Ai, Br, Bi, t.r0, t.i0);                       // d=64 (in-register)
    xswap32(Ar, Br); xswap32(Ai, Bi);
    bfly(Ar, Ai, Br, Bi, t.r1, t.i1);                       // d=32 (VALU permlane)
    xswap16(Ar, Br); xswap16(Ai, Bi);
    bfly(Ar, Ai, Br, Bi, t.r2, t.i2);                       // d=16 (VALU permlane)
    pswap_sw<0x201F>(Ar, Br, u8); pswap_sw<0x201F>(Ai, Bi, u8);
    bfly(Ar, Ai, Br, Bi, t.r3, t.i3);                       // d=8  (ds_swizzle)
    pswap_sw<0x101F>(Ar, Br, u4); pswap_sw<0x101F>(Ai, Bi, u4);
    bfly(Ar, Ai, Br, Bi, t.r4, t.i4);                       // d=4  (ds_swizzle)
    pswap_dpp<0x4E>(Ar, Br, u2); pswap_dpp<0x4E>(Ai, Bi, u2);
    bfly(Ar, Ai, Br, Bi, t.r5, t.i5);                       // d=2  (DPP)
    pswap_dpp<0xB1>(Ar, Br, u1); pswap_dpp<0xB1>(Ai, Bi, u1);
    {   // d=1, tw = 1
        float sr = Ar + Br, si = Ai + Bi;
        float dr = Ar - Br, di = Ai - Bi;
        Ar = sr; Ai = si; Br = dr; Bi = di;
    }
}

// ---------- Stage A: forward FFT (real-packed rows) + fftshift + central-mag ----------
__global__ __launch_bounds__(1024) void fft_fwd(const float* __restrict__ x,
                                                ushortt* __restrict__ xfRe,
                                                ushortt* __restrict__ xfIm,
                                                float* __restrict__ magc) {
    __shared__ float2 sc[128][129];
    __shared__ float twr[64], twi[64];
    int img = blockIdx.x;
    int tid = threadIdx.x, l = tid & 63, wv = tid >> 6;
    if (tid < 64) {
        float s, c;
        sincosf(-PIf * (float)tid / 64.0f, &s, &c);
        twr[tid] = c; twi[tid] = s;
    }
    const float* xi = x + (size_t)img * HW;
    __syncthreads();

    TwSet t = load_tw(twr, twi, l);
    bool u8 = (l & 8) != 0, u4 = (l & 4) != 0, u2 = (l & 2) != 0, u1 = (l & 1) != 0;
    int e = brev6(l);

    // ---- row pass: all loads issued upfront (latency hiding), 4 pair-FFTs
    float lar[4], lai[4], lbr[4], lbi[4];
    #pragma unroll
    for (int r = 0; r < 4; ++r) {
        int p = wv * 4 + r;
        lar[r] = xi[(2 * p) * 128 + l];
        lai[r] = xi[(2 * p + 1) * 128 + l];
        lbr[r] = xi[(2 * p) * 128 + 64 + l];
        lbi[r] = xi[(2 * p + 1) * 128 + 64 + l];
    }
    #pragma unroll
    for (int r = 0; r < 4; ++r) {
        int p = wv * 4 + r;
        float Ar = lar[r], Ai = lai[r], Br = lbr[r], Bi = lbi[r];
        fft128_ps(Ar, Ai, Br, Bi, t, u8, u4, u2, u1);
        sc[p][e]      = make_float2(Ar, Ai);   // Z_p natural order, rows 0..63
        sc[p][e + 64] = make_float2(Br, Bi);
    }
    __syncthreads();

    // ---- col pass: unpack rows from Z symmetry, FFT, stage in regs
    float oar[8], oai[8], obr[8], obi[8];
    int pa = l >> 1, pb = 32 + (l >> 1);
    bool odd = (l & 1) != 0;
    #pragma unroll
    for (int r = 0; r < 8; ++r) {
        int c = wv * 8 + r, cm = (128 - c) & 127;
        float2 Za = sc[pa][c], Zma = sc[pa][cm];
        float2 Zb = sc[pb][c], Zmb = sc[pb][cm];
        float Ar = odd ? (Za.y + Zma.y) : (Za.x + Zma.x);
        float Ai = odd ? (Zma.x - Za.x) : (Za.y - Zma.y);
        float Br = odd ? (Zb.y + Zmb.y) : (Zb.x + Zmb.x);
        float Bi = odd ? (Zmb.x - Zb.x) : (Zb.y - Zmb.y);
        fft128_ps(Ar, Ai, Br, Bi, t, u8, u4, u2, u1);
        oar[r] = Ar; oai[r] = Ai; obr[r] = Br; obi[r] = Bi;
    }
    __syncthreads();
    #pragma unroll
    for (int r = 0; r < 8; ++r) {
        int c = wv * 8 + r;
        sc[e][c]      = make_float2(oar[r], oai[r]);
        sc[e + 64][c] = make_float2(obr[r], obi[r]);
    }
    __syncthreads();

    // coalesced fftshift'd bf16 write (ortho 1/128, plus 1/2 unpack fold -> 1/256)
    uint32* oRe = (uint32*)(xfRe + ((size_t)img << 14));
    uint32* oIm = (uint32*)(xfIm + ((size_t)img << 14));
    for (int idx2 = tid; idx2 < 8192; idx2 += 1024) {
        int p = idx2 >> 6, qp = idx2 & 63, q = qp * 2;
        int u  = (p + 64) & 127;
        int v0 = (q + 64) & 127;          // even, pair contiguous
        const float scl = 1.0f / 256.0f;
        float2 e0 = sc[u][v0], e1 = sc[u][v0 + 1];
        uint32 re = (uint32)f2bf(e0.x * scl) | ((uint32)f2bf(e1.x * scl) << 16);
        uint32 im = (uint32)f2bf(e0.y * scl) | ((uint32)f2bf(e1.y * scl) << 16);
        oRe[p * 64 + qp] = re;
        oIm[p * 64 + qp] = im;
    }
    // central 7x7 |xf| accumulation (fp32)
    if (tid < 49) {
        int p = 61 + tid / 7, q = 61 + tid % 7;
        int u = (p + 64) & 127, v = (q + 64) & 127;
        float2 z = sc[u][v];
        float mag = sqrtf(z.x * z.x + z.y * z.y) * (1.0f / 256.0f);
        atomicAdd(&magc[(img >> 8) * 49 + tid], mag);
    }
}

// ---------- Stage B: tiny MLP + anisotropic kernel build (pre-paired taps) ----------
__global__ __launch_bounds__(256) void mlp_kern(const float* __restrict__ magc,
                                                const float* __restrict__ w1,
                                                const float* __restrict__ b1,
                                                const float* __restrict__ w2,
                                                const float* __restrict__ b2,
                                                float2* __restrict__ kern_pk) {
    __shared__ float hid[8][32];
    __shared__ float par[8][3];
    __shared__ float kun[8][49];
    __shared__ float ksum[8];
    int tid = threadIdx.x;
    {
        int b = tid >> 5, n = tid & 31;
        float acc = b1[n];
        for (int i = 0; i < 49; ++i)
            acc = fmaf(magc[b * 49 + i] * (1.0f / 256.0f), w1[i * 32 + n], acc);
        hid[b][n] = fmaxf(acc, 0.f);
    }
    __syncthreads();
    if (tid < 24) {
        int b = tid / 3, j = tid % 3;
        float acc = b2[j];
        for (int n = 0; n < 32; ++n) acc = fmaf(hid[b][n], w2[n * 3 + j], acc);
        par[b][j] = acc;
    }
    __syncthreads();
    for (int idx = tid; idx < 392; idx += 256) {
        int b = idx / 49, ij = idx % 49;
        int i = ij / 7, j2 = ij % 7;
        float p0 = par[b][0], p1 = par[b][1], p2 = par[b][2];
        float theta = atan2f(p0, p1) * 0.5f + PIf * 0.5f;
        float lam1 = expf(p2);
        float lam2 = 1.0f / (lam1 + 1e-8f);
        float yy = (float)(i - 3), xx = (float)(j2 - 3);
        float ct, st;
        sincosf(theta, &st, &ct);
        float xr =  xx * ct + yy * st;
        float yr = -xx * st + yy * ct;
        kun[b][ij] = expf(-(xr * xr / (2.f * lam1 * lam1) + yr * yr / (2.f * lam2 * lam2)));
    }
    __syncthreads();
    if (tid < 8) {
        float s = 0.f;
        for (int t = 0; t < 49; ++t) s += kun[tid][t];
        ksum[tid] = s + 1e-8f;
    }
    __syncthreads();
    for (int idx = tid; idx < 448; idx += 256) {
        int b  = idx / 56;
        int r7 = idx - b * 56;
        int rr = r7 / 7, dx = r7 - rr * 7;
        float inv = 1.0f / ksum[b];
        float v0 = (rr < 7)  ? kun[b][rr * 7 + dx] * inv       : 0.f;
        float v1 = (rr >= 1) ? kun[b][(rr - 1) * 7 + dx] * inv : 0.f;
        kern_pk[idx] = make_float2(v0, v1);
    }
}

// ---------- Stage C: channel mixing via bf16 MFMA, direct [c][pix] input ----------
__global__ __launch_bounds__(256) void gemm_mix(const ushortt* __restrict__ xfRe,
                                                const ushortt* __restrict__ xfIm,
                                                const float* __restrict__ wr,
                                                ushortt* __restrict__ mixRe,
                                                ushortt* __restrict__ mixIm) {
    __shared__ ushortt lA[2][5120];   // [o=128][k=32] stride 40 ushorts
    __shared__ uint32  lB[2][2560];   // [pix=128][k2=16(+4 pad)] dwords, swizzled
    int tid = threadIdx.x;
    int lane = tid & 63, wave = tid >> 6;
    int wm = wave >> 1, wn = wave & 1;
    int l15 = lane & 15, q4 = lane >> 4;
    int b = blockIdx.z >> 1, part = blockIdx.z & 1;
    const ushortt* Xb = (part ? xfIm : xfRe) + (size_t)b * (256 * HW)
                        + blockIdx.x * 128;
    ushortt* Dst = (part ? mixIm : mixRe) + (size_t)b * (256 * HW)
                   + (size_t)(blockIdx.y * 128) * HW + blockIdx.x * 128;
    const float* W = wr + (blockIdx.y * 128) * 256;

    int srow = tid >> 1, shalf = tid & 1;
    const float* wRow = W + srow * 256 + shalf * 16;
    int ldsOffA = srow * 40 + shalf * 16;

    int kt = tid >> 4;                 // 0..15
    int pq = tid & 15;                 // 0..15
    int kswz = kt ^ ((pq & 3) << 2);   // octet-bit XOR swizzle
    int rowbase = pq * 160;            // pq*8 rows * 20 dwords

    float4 wreg[4];
    uint4  a0, a1;
    #pragma unroll
    for (int i = 0; i < 4; ++i) wreg[i] = *(const float4*)(wRow + i * 4);
    {
        const ushortt* xp = Xb + (size_t)(2 * kt) * HW + pq * 8;
        a0 = *(const uint4*)xp;
        a1 = *(const uint4*)(xp + HW);
    }

    f32x4 acc[4][4];
    #pragma unroll
    for (int i = 0; i < 4; ++i)
        #pragma unroll
        for (int j = 0; j < 4; ++j)
            #pragma unroll
            for (int k = 0; k < 4; ++k) acc[i][j][k] = 0.f;

    int abase = (wm * 64 + l15) * 40 + q4 * 8;
    int baddr[4];
    #pragma unroll
    for (int f = 0; f < 4; ++f) {
        int pf = wn * 64 + f * 16 + l15;
        baddr[f] = pf * 40 + ((q4 ^ ((pf >> 3) & 3)) << 3);
    }

    for (int kb = 0; kb < 8; ++kb) {
        int bufc = kb & 1;
        {
            float ff[16] = {wreg[0].x, wreg[0].y, wreg[0].z, wreg[0].w,
                            wreg[1].x, wreg[1].y, wreg[1].z, wreg[1].w,
                            wreg[2].x, wreg[2].y, wreg[2].z, wreg[2].w,
                            wreg[3].x, wreg[3].y, wreg[3].z, wreg[3].w};
            uint32 p[8];
            #pragma unroll
            for (int j = 0; j < 8; ++j)
                p[j] = (uint32)f2bf(ff[2 * j]) | ((uint32)f2bf(ff[2 * j + 1]) << 16);
            *(uint4*)&lA[bufc][ldsOffA]     = make_uint4(p[0], p[1], p[2], p[3]);
            *(uint4*)&lA[bufc][ldsOffA + 8] = make_uint4(p[4], p[5], p[6], p[7]);
        }
        {
            uint32 d[8];
            d[0] = (a0.x & 0xffffu) | (a1.x << 16);
            d[1] = (a0.x >> 16)     | (a1.x & 0xffff0000u);
            d[2] = (a0.y & 0xffffu) | (a1.y << 16);
            d[3] = (a0.y >> 16)     | (a1.y & 0xffff0000u);
            d[4] = (a0.z & 0xffffu) | (a1.z << 16);
            d[5] = (a0.z >> 16)     | (a1.z & 0xffff0000u);
            d[6] = (a0.w & 0xffffu) | (a1.w << 16);
            d[7] = (a0.w >> 16)     | (a1.w & 0xffff0000u);
            uint32* lb = lB[bufc];
            #pragma unroll
            for (int j = 0; j < 8; ++j) lb[rowbase + j * 20 + kswz] = d[j];
        }
        __syncthreads();
        if (kb < 7) {
            const float* wN = wRow + (kb + 1) * 32;
            #pragma unroll
            for (int i = 0; i < 4; ++i) wreg[i] = *(const float4*)(wN + i * 4);
            const ushortt* xp = Xb + (size_t)((kb + 1) * 32 + 2 * kt) * HW + pq * 8;
            a0 = *(const uint4*)xp;
            a1 = *(const uint4*)(xp + HW);
        }
        short8 af[4], bf[4];
        const ushortt* lbU = (const ushortt*)lB[bufc];
        #pragma unroll
        for (int f = 0; f < 4; ++f) af[f] = *(const short8*)&lA[bufc][abase + f * 640];
        #pragma unroll
        for (int f = 0; f < 4; ++f) bf[f] = *(const short8*)&lbU[baddr[f]];
        #pragma unroll
        for (int fi = 0; fi < 4; ++fi)
            #pragma unroll
            for (int fj = 0; fj < 4; ++fj)
                acc[fi][fj] = __builtin_amdgcn_mfma_f32_16x16x32_bf16(
                    af[fi], bf[fj], acc[fi][fj], 0, 0, 0);
    }
    #pragma unroll
    for (int fi = 0; fi < 4; ++fi) {
        #pragma unroll
        for (int r = 0; r < 4; ++r) {
            int o_l = wm * 64 + fi * 16 + q4 * 4 + r;
            ushortt* dp = Dst + (size_t)o_l * HW + wn * 64 + l15;
            #pragma unroll
            for (int fj = 0; fj < 4; ++fj)
                dp[fj * 16] = f2bf(acc[fi][fj][r]);
        }
    }
}

// ---------- Stage D: 7x7 zero-padded conv, packed-fp32 dual-row FMA ----------
// Tile stride 73 (ODD): read banks = (146g + 8s) mod 32 -> exactly 2 lanes/bank
// (free, m136). Staging stores are two adjacent scalar floats (ds_write2_b32,
// 4B-align) instead of float2 (which forced stride 74 = 8-way read conflicts).
__global__ __launch_bounds__(256) void conv7(const ushortt* __restrict__ mixRe,
                                             const ushortt* __restrict__ mixIm,
                                             const float2* __restrict__ kern_pk,
                                             ushortt* __restrict__ outRe,
                                             ushortt* __restrict__ outIm) {
    __shared__ float tile[70 * 73];
    int b = blockIdx.z;
    int plane = blockIdx.y;
    int part = plane >> 8;
    size_t pbase = ((size_t)(b * 256 + (plane & 255))) << 14;
    const ushortt* src = (part ? mixIm : mixRe) + pbase;
    ushortt* dst = (part ? outIm : outRe) + pbase;
    int ty = (blockIdx.x >> 1) * 64, tx = (blockIdx.x & 1) * 64;
    int tid = threadIdx.x;
    const float2* kp = kern_pk + b * 56;

    for (int idx = tid; idx < 2520; idx += 256) {
        int row = idx / 36, du = idx - row * 36;
        int gy = ty + row - 3, gx0 = tx - 4 + 2 * du;
        uint32 v = 0u;
        if ((unsigned)gy < 128u && (unsigned)gx0 < 128u)
            v = *(const uint32*)(src + gy * 128 + gx0);
        int base = row * 73 + 2 * du;
        tile[base]     = __uint_as_float(v << 16);
        tile[base + 1] = __uint_as_float(v & 0xffff0000u);
    }
    __syncthreads();

    int ox = (tid & 7) * 8, oy = (tid >> 3) * 2;
    f32x2 acc2[8];
    #pragma unroll
    for (int j = 0; j < 8; ++j) { acc2[j].x = 0.f; acc2[j].y = 0.f; }

    #pragma unroll
    for (int dyy = 0; dyy < 8; ++dyy) {
        float row[14];
        #pragma unroll
        for (int m = 0; m < 14; ++m) row[m] = tile[(oy + dyy) * 73 + ox + 1 + m];
        #pragma unroll
        for (int dx = 0; dx < 7; ++dx) {
            float2 kl = kp[dyy * 7 + dx];
            f32x2 kk; kk.x = kl.x; kk.y = kl.y;
            #pragma unroll
            for (int j = 0; j < 8; ++j) {
                f32x2 rr; rr.x = row[dx + j]; rr.y = row[dx + j];
                acc2[j] = __builtin_elementwise_fma(rr, kk, acc2[j]);
            }
        }
    }

    uint32 s0[4], s1[4];
    #pragma unroll
    for (int m = 0; m < 4; ++m) {
        s0[m] = (uint32)f2bf(acc2[2 * m].x) | ((uint32)f2bf(acc2[2 * m + 1].x) << 16);
        s1[m] = (uint32)f2bf(acc2[2 * m].y) | ((uint32)f2bf(acc2[2 * m + 1].y) << 16);
    }
    *(uint4*)(dst + (ty + oy) * 128 + tx + ox)     = make_uint4(s0[0], s0[1], s0[2], s0[3]);
    *(uint4*)(dst + (ty + oy + 1) * 128 + tx + ox) = make_uint4(s1[0], s1[1], s1[2], s1[3]);
}

// ---------- Stage E: ifftshift + IFFT (conj trick, paired real-output cols) + x ----------
__global__ __launch_bounds__(1024) void ifft_add(const ushortt* __restrict__ convRe,
                                                 const ushortt* __restrict__ convIm,
                                                 const float* __restrict__ x,
                                                 float* __restrict__ out) {
    __shared__ float2 sc[128][129];
    __shared__ float twr[64], twi[64];
    int img = blockIdx.x;
    int tid = threadIdx.x, l = tid & 63, wv = tid >> 6;
    if (tid < 64) {
        float s, c;
        sincosf(-PIf * (float)tid / 64.0f, &s, &c);
        twr[tid] = c; twi[tid] = s;
    }
    const ushortt* cr = convRe + ((size_t)img << 14);
    const ushortt* ci = convIm + ((size_t)img << 14);
    __syncthreads();

    TwSet t = load_tw(twr, twi, l);
    bool u8 = (l & 8) != 0, u4 = (l & 4) != 0, u2 = (l & 2) != 0, u1 = (l & 1) != 0;
    int e = brev6(l);

    // ---- row pass: ifftshift gather (conj), ALL loads upfront, 8 FFTs
    {
        float nar[8], nai[8], nbr[8], nbi[8];
        #pragma unroll
        for (int r = 0; r < 8; ++r) {
            int p = ((wv * 8 + r) + 64) & 127;
            nar[r] = bf2f(cr[p * 128 + 64 + l]);
            nai[r] = bf2f(ci[p * 128 + 64 + l]);
            nbr[r] = bf2f(cr[p * 128 + l]);
            nbi[r] = bf2f(ci[p * 128 + l]);
        }
        #pragma unroll
        for (int r = 0; r < 8; ++r) {
            int u = wv * 8 + r;
            float Ar = nar[r], Ai = -nai[r], Br = nbr[r], Bi = -nbi[r];
            fft128_ps(Ar, Ai, Br, Bi, t, u8, u4, u2, u1);
            sc[u][e]      = make_float2(Ar, Ai);
            sc[u][e + 64] = make_float2(Br, Bi);
        }
    }
    __syncthreads();

    // ---- col pass: 4 column-PAIR FFTs per wave, staged in regs
    float oar[4], oai[4], obr[4], obi[4];
    int rv  = (128 - l) & 127;       // reverse of row l
    int rv2 = (64 - l) & 127;        // reverse of row l+64
    #pragma unroll
    for (int r = 0; r < 4; ++r) {
        int m = wv * 4 + r;
        int c0 = 2 * m, c1 = 2 * m + 1;
        float2 P  = sc[l][c0],      R  = sc[l][c1];
        float2 Q  = sc[rv][c0],     S  = sc[rv][c1];
        float2 P2 = sc[l + 64][c0], R2 = sc[l + 64][c1];
        float2 Q2 = sc[rv2][c0],    S2 = sc[rv2][c1];
        float Ar = P.x + Q.x - R.y + S.y;
        float Ai = P.y - Q.y + R.x + S.x;
        float Br = P2.x + Q2.x - R2.y + S2.y;
        float Bi = P2.y - Q2.y + R2.x + S2.x;
        fft128_ps(Ar, Ai, Br, Bi, t, u8, u4, u2, u1);
        oar[r] = Ar; oai[r] = Ai; obr[r] = Br; obi[r] = Bi;
    }
    __syncthreads();
    #pragma unroll
    for (int r = 0; r < 4; ++r) {
        int m = wv * 4 + r;
        sc[e][m]      = make_float2(oar[r], oai[r]);   // (.x=col 2m, .y=col 2m+1)
        sc[e + 64][m] = make_float2(obr[r], obi[r]);
    }
    __syncthreads();

    // ---- output: slot m -> columns (2m, 2m+1); scale 1/256 (conj-trick 1/128 * pack 1/2)
    const float* xi = x + (size_t)img * HW;
    float* oo = out + (size_t)img * HW;
    for (int idx2 = tid; idx2 < 8192; idx2 += 1024) {
        int y = idx2 >> 6, m = idx2 & 63;
        float2 v = sc[y][m];
        float2 xv = *(const float2*)(xi + y * 128 + 2 * m);
        float2 ov;
        ov.x = v.x * (1.0f / 256.0f) + xv.x;
        ov.y = v.y * (1.0f / 256.0f) + xv.y;
        *(float2*)(oo + y * 128 + 2 * m) = ov;
    }
}

extern "C" void kernel_launch(void* const* d_in, const int* in_sizes, int n_in,
                              void* d_out, int out_size, void* d_ws, size_t ws_size,
                              hipStream_t stream) {
    const float* x  = (const float*)d_in[0];
    const float* w1 = (const float*)d_in[1];
    const float* b1 = (const float*)d_in[2];
    const float* w2 = (const float*)d_in[3];
    const float* b2 = (const float*)d_in[4];
    const float* wr = (const float*)d_in[5];

    char* ws = (char*)d_ws;
    ushortt* xfRe  = (ushortt*)ws;                       // 64 MiB
    ushortt* xfIm  = xfRe + 33554432;                    // 64 MiB
    ushortt* mixRe = (ushortt*)(ws + 134217728);         // 64 MiB (separate: gemm in != out)
    ushortt* mixIm = mixRe + 33554432;                   // 64 MiB
    ushortt* convRe = xfRe, *convIm = xfIm;              // aliases (xf dead after gemm)
    float* magc = (float*)(ws + 268435456);
    float2* kern_pk = (float2*)(ws + 268435456 + 2048);  // 448 float2 = 3584 B

    hipMemsetAsync(magc, 0, 392 * sizeof(float), stream);
    fft_fwd<<<2048, 1024, 0, stream>>>(x, xfRe, xfIm, magc);
    mlp_kern<<<1, 256, 0, stream>>>(magc, w1, b1, w2, b2, kern_pk);
    gemm_mix<<<dim3(128, 2, 16), 256, 0, stream>>>(xfRe, xfIm, wr, mixRe, mixIm);
    conv7<<<dim3(4, 512, 8), 256, 0, stream>>>(mixRe, mixIm, kern_pk, convRe, convIm);
    ifft_add<<<2048, 1024, 0, stream>>>(convRe, convIm, x, (float*)d_out);
}